// Round 1
// baseline (928.605 us; speedup 1.0000x reference)
//
#include <hip/hip_runtime.h>
#include <math.h>

#define NU 100000
#define NI 50000
#define NN 150000
#define D 128
#define NE 1000000
#define CD 768
#define BATCH 4096

static inline size_t alignup(size_t x, size_t a) { return (x + a - 1) / a * a; }

// ---------------- degree / normalization ----------------

__global__ void deg_count_kernel(const int* __restrict__ dst, const float* __restrict__ ew,
                                 float* __restrict__ degw, int* __restrict__ cnt) {
  int i = blockIdx.x * blockDim.x + threadIdx.x;
  int stride = gridDim.x * blockDim.x;
  for (; i < NE; i += stride) {
    int d = dst[i];
    atomicAdd(&degw[d], ew[i]);
    atomicAdd(&cnt[d], 1);
  }
}

__global__ void dinv_kernel(float* __restrict__ degw) {
  int i = blockIdx.x * blockDim.x + threadIdx.x;
  if (i < NN) {
    float v = degw[i];
    degw[i] = (v > 0.f) ? rsqrtf(v) : 0.f;
  }
}

// ---------------- prefix scan for CSR row_ptr ----------------

__global__ void scan_p1(const int* __restrict__ cnt, int* __restrict__ bsum) {
  __shared__ int s[256];
  int b = blockIdx.x;
  int i = b * 256 + threadIdx.x;
  s[threadIdx.x] = (i < NN) ? cnt[i] : 0;
  __syncthreads();
  for (int off = 128; off; off >>= 1) {
    if (threadIdx.x < off) s[threadIdx.x] += s[threadIdx.x + off];
    __syncthreads();
  }
  if (threadIdx.x == 0) bsum[b] = s[0];
}

__global__ void scan_p2(int* __restrict__ bsum, int nb) {
  if (threadIdx.x == 0 && blockIdx.x == 0) {
    int run = 0;
    for (int b = 0; b < nb; ++b) { int t = bsum[b]; bsum[b] = run; run += t; }
  }
}

__global__ void scan_p3(const int* __restrict__ cnt, const int* __restrict__ bsum,
                        int* __restrict__ row_ptr) {
  __shared__ int s[256];
  int b = blockIdx.x;
  int i = b * 256 + threadIdx.x;
  s[threadIdx.x] = (i < NN) ? cnt[i] : 0;
  __syncthreads();
  for (int off = 1; off < 256; off <<= 1) {
    int t = (threadIdx.x >= off) ? s[threadIdx.x - off] : 0;
    __syncthreads();
    s[threadIdx.x] += t;
    __syncthreads();
  }
  if (i < NN) row_ptr[i + 1] = bsum[b] + s[threadIdx.x];
  if (i == 0) row_ptr[0] = 0;
}

__global__ void csr_fill(const int* __restrict__ src, const int* __restrict__ dst,
                         const float* __restrict__ ew, const float* __restrict__ dinv,
                         int* __restrict__ cursor, int* __restrict__ csrc,
                         float* __restrict__ cnorm) {
  int i = blockIdx.x * blockDim.x + threadIdx.x;
  int stride = gridDim.x * blockDim.x;
  for (; i < NE; i += stride) {
    int s = src[i], d = dst[i];
    float nm = dinv[s] * ew[i] * dinv[d];
    int p = atomicAdd(&cursor[d], 1);
    csrc[p] = s;
    cnorm[p] = nm;
  }
}

// ---------------- propagation layers ----------------
// MODE 0: gather from embeddings, write y, OUT = x0 + y
// MODE 1: gather from xsrc, write y, OUT += y
// MODE 2: gather from xsrc, OUT = (OUT + y) * 0.25
template <int MODE>
__global__ __launch_bounds__(256) void layer_kernel(
    const int* __restrict__ row_ptr, const int* __restrict__ csrc,
    const float* __restrict__ cnorm, const float* __restrict__ xsrc,
    const float* __restrict__ uemb, const float* __restrict__ iemb,
    float* __restrict__ y, float* __restrict__ OUT) {
  int wv = threadIdx.x >> 6, lane = threadIdx.x & 63;
  int n = blockIdx.x * 4 + wv;
  if (n >= NN) return;
  int beg = row_ptr[n], end = row_ptr[n + 1];
  float a0 = 0.f, a1 = 0.f;
  for (int j = beg; j < end; ++j) {
    int s = csrc[j];
    float w = cnorm[j];
    const float* xs;
    if (MODE == 0)
      xs = (s < NU) ? (uemb + (size_t)s * D) : (iemb + (size_t)(s - NU) * D);
    else
      xs = xsrc + (size_t)s * D;
    a0 = fmaf(w, xs[lane], a0);
    a1 = fmaf(w, xs[lane + 64], a1);
  }
  size_t o = (size_t)n * D + lane;
  if (MODE == 0) {
    float x00, x01;
    if (n < NU) { x00 = uemb[o]; x01 = uemb[o + 64]; }
    else        { x00 = iemb[o - (size_t)NU * D]; x01 = iemb[o + 64 - (size_t)NU * D]; }
    y[o] = a0; y[o + 64] = a1;
    OUT[o] = x00 + a0; OUT[o + 64] = x01 + a1;
  } else if (MODE == 1) {
    y[o] = a0; y[o + 64] = a1;
    OUT[o] += a0; OUT[o + 64] += a1;
  } else {
    OUT[o] = (OUT[o] + a0) * 0.25f;
    OUT[o + 64] = (OUT[o + 64] + a1) * 0.25f;
  }
}

// ---------------- content projection + align MSE (fused) ----------------
// proj[i][d] = sum_k content[i][k] * W[d][k];  align += (ifinal[i][d]-proj)^2
__global__ __launch_bounds__(256) void align_kernel(
    const float* __restrict__ content, const float* __restrict__ W,
    const float* __restrict__ ifinal, float* __restrict__ accums) {
  __shared__ float a_s[16][64];
  __shared__ float b_s[16][128];
  int tid = threadIdx.x;
  int i0 = blockIdx.x * 64;
  int tx = tid & 31, ty = tid >> 5;
  float acc[8][4];
#pragma unroll
  for (int r = 0; r < 8; ++r)
#pragma unroll
    for (int c = 0; c < 4; ++c) acc[r][c] = 0.f;

  for (int k0 = 0; k0 < CD; k0 += 16) {
    {
      int ii = tid >> 2, kq = tid & 3;
      float4 v = make_float4(0.f, 0.f, 0.f, 0.f);
      int it = i0 + ii;
      if (it < NI) v = *(const float4*)(content + (size_t)it * CD + k0 + kq * 4);
      a_s[kq * 4 + 0][ii] = v.x; a_s[kq * 4 + 1][ii] = v.y;
      a_s[kq * 4 + 2][ii] = v.z; a_s[kq * 4 + 3][ii] = v.w;
    }
    {
      int dd = tid >> 2, kq = tid & 3;
#pragma unroll
      for (int p = 0; p < 2; ++p) {
        int d = dd + p * 64;
        float4 v = *(const float4*)(W + (size_t)d * CD + k0 + kq * 4);
        b_s[kq * 4 + 0][d] = v.x; b_s[kq * 4 + 1][d] = v.y;
        b_s[kq * 4 + 2][d] = v.z; b_s[kq * 4 + 3][d] = v.w;
      }
    }
    __syncthreads();
#pragma unroll
    for (int k = 0; k < 16; ++k) {
      float4 b = *(const float4*)&b_s[k][tx * 4];
      float4 alo = *(const float4*)&a_s[k][ty * 8];
      float4 ahi = *(const float4*)&a_s[k][ty * 8 + 4];
      float av[8] = {alo.x, alo.y, alo.z, alo.w, ahi.x, ahi.y, ahi.z, ahi.w};
#pragma unroll
      for (int r = 0; r < 8; ++r) {
        acc[r][0] = fmaf(av[r], b.x, acc[r][0]);
        acc[r][1] = fmaf(av[r], b.y, acc[r][1]);
        acc[r][2] = fmaf(av[r], b.z, acc[r][2]);
        acc[r][3] = fmaf(av[r], b.w, acc[r][3]);
      }
    }
    __syncthreads();
  }

  float s = 0.f;
#pragma unroll
  for (int r = 0; r < 8; ++r) {
    int it = i0 + ty * 8 + r;
    if (it < NI) {
      const float* row = ifinal + (size_t)it * D + tx * 4;  // 4B-aligned only
#pragma unroll
      for (int c = 0; c < 4; ++c) {
        float diff = row[c] - acc[r][c];
        s = fmaf(diff, diff, s);
      }
    }
  }
  for (int off = 32; off; off >>= 1) s += __shfl_down(s, off);
  __shared__ float wsum[4];
  int wv = tid >> 6, lane = tid & 63;
  if (lane == 0) wsum[wv] = s;
  __syncthreads();
  if (tid == 0) atomicAdd(&accums[2], wsum[0] + wsum[1] + wsum[2] + wsum[3]);
}

// ---------------- BPR + reg loss over batch ----------------
__global__ __launch_bounds__(256) void loss_batch(
    const int* __restrict__ bu, const int* __restrict__ bp, const int* __restrict__ bn,
    const float* __restrict__ OUT, float* __restrict__ accums) {
  int wv = threadIdx.x >> 6, lane = threadIdx.x & 63;
  int b = blockIdx.x * 4 + wv;
  if (b >= BATCH) return;
  const float* u = OUT + (size_t)bu[b] * D;
  const float* ip = OUT + ((size_t)NU + bp[b]) * D;
  const float* in_ = OUT + ((size_t)NU + bn[b]) * D;
  float u0 = u[lane], u1 = u[lane + 64];
  float p0 = ip[lane], p1 = ip[lane + 64];
  float n0 = in_[lane], n1 = in_[lane + 64];
  float ps = u0 * p0 + u1 * p1;
  float ns = u0 * n0 + u1 * n1;
  float rg = u0 * u0 + u1 * u1 + p0 * p0 + p1 * p1 + n0 * n0 + n1 * n1;
  for (int off = 32; off; off >>= 1) {
    ps += __shfl_down(ps, off);
    ns += __shfl_down(ns, off);
    rg += __shfl_down(rg, off);
  }
  if (lane == 0) {
    float x = ns - ps;  // -(ps-ns)
    float sp = fmaxf(x, 0.f) + log1pf(expf(-fabsf(x)));
    atomicAdd(&accums[0], sp);
    atomicAdd(&accums[1], rg);
  }
}

__global__ void finalize_kernel(const float* __restrict__ accums, float* __restrict__ out0) {
  if (threadIdx.x == 0 && blockIdx.x == 0) {
    float bpr = accums[0] / (float)BATCH;
    float reg = (accums[1] / (float)BATCH) * 1e-4f;
    float align = accums[2] / (float)((size_t)NI * D);
    out0[0] = bpr + reg + 0.1f * align;
  }
}

// ---------------- launch ----------------
extern "C" void kernel_launch(void* const* d_in, const int* in_sizes, int n_in,
                              void* d_out, int out_size, void* d_ws, size_t ws_size,
                              hipStream_t stream) {
  const int* edge_index = (const int*)d_in[0];
  const float* ew = (const float*)d_in[1];
  const int* bu = (const int*)d_in[2];
  const int* bp = (const int*)d_in[3];
  const int* bn = (const int*)d_in[4];
  const float* content = (const float*)d_in[5];
  const float* uemb = (const float*)d_in[6];
  const float* iemb = (const float*)d_in[7];
  const float* W = (const float*)d_in[8];
  const int* src = edge_index;
  const int* dst = edge_index + NE;
  float* outf = (float*)d_out;
  float* OUT = outf + 1;  // [NN][D], users then items

  char* ws = (char*)d_ws;
  size_t off = 0;
  auto alloc = [&](size_t bytes) {
    void* p = ws + off;
    off = alignup(off + bytes, 256);
    return p;
  };
  float* bufA = (float*)alloc((size_t)NN * D * 4);
  float* bufB = (float*)alloc((size_t)NN * D * 4);
  float* degw = (float*)alloc((size_t)NN * 4);
  int* cnt = (int*)alloc((size_t)NN * 4);
  int* row_ptr = (int*)alloc((size_t)(NN + 1) * 4);
  int* cursor = (int*)alloc((size_t)NN * 4);
  int NB = (NN + 255) / 256;
  int* bsum = (int*)alloc((size_t)NB * 4);
  int* csrc = (int*)alloc((size_t)NE * 4);
  float* cnorm = (float*)alloc((size_t)NE * 4);
  float* accums = (float*)alloc(16);

  hipMemsetAsync(degw, 0, (size_t)NN * 4, stream);
  hipMemsetAsync(cnt, 0, (size_t)NN * 4, stream);
  hipMemsetAsync(accums, 0, 16, stream);

  deg_count_kernel<<<2048, 256, 0, stream>>>(dst, ew, degw, cnt);
  dinv_kernel<<<(NN + 255) / 256, 256, 0, stream>>>(degw);
  scan_p1<<<NB, 256, 0, stream>>>(cnt, bsum);
  scan_p2<<<1, 64, 0, stream>>>(bsum, NB);
  scan_p3<<<NB, 256, 0, stream>>>(cnt, bsum, row_ptr);
  hipMemcpyAsync(cursor, row_ptr, (size_t)NN * 4, hipMemcpyDeviceToDevice, stream);
  csr_fill<<<2048, 256, 0, stream>>>(src, dst, ew, degw, cursor, csrc, cnorm);

  int LB = (NN + 3) / 4;
  layer_kernel<0><<<LB, 256, 0, stream>>>(row_ptr, csrc, cnorm, nullptr, uemb, iemb, bufA, OUT);
  layer_kernel<1><<<LB, 256, 0, stream>>>(row_ptr, csrc, cnorm, bufA, uemb, iemb, bufB, OUT);
  layer_kernel<2><<<LB, 256, 0, stream>>>(row_ptr, csrc, cnorm, bufB, uemb, iemb, nullptr, OUT);

  align_kernel<<<(NI + 63) / 64, 256, 0, stream>>>(content, W, OUT + (size_t)NU * D, accums);
  loss_batch<<<(BATCH + 3) / 4, 256, 0, stream>>>(bu, bp, bn, OUT, accums);
  finalize_kernel<<<1, 64, 0, stream>>>(accums, outf);
}

// Round 2
// 750.756 us; speedup vs baseline: 1.2369x; 1.2369x over previous
//
#include <hip/hip_runtime.h>
#include <math.h>

#define NU 100000
#define NI 50000
#define NN 150000
#define D 128
#define NE 1000000
#define CD 768
#define BATCH 4096

typedef short bf16x8 __attribute__((ext_vector_type(8)));
typedef float f32x4 __attribute__((ext_vector_type(4)));

static inline size_t alignup(size_t x, size_t a) { return (x + a - 1) / a * a; }

__device__ inline unsigned short f2bf(float f) {
  unsigned int u = __builtin_bit_cast(unsigned int, f);
  unsigned int r = (u + 0x7fffu + ((u >> 16) & 1u)) >> 16;
  return (unsigned short)r;
}

// ---------------- degree / normalization ----------------

__global__ void deg_count_kernel(const int* __restrict__ dst, const float* __restrict__ ew,
                                 float* __restrict__ degw, int* __restrict__ cnt) {
  int i = blockIdx.x * blockDim.x + threadIdx.x;
  int stride = gridDim.x * blockDim.x;
  for (; i < NE; i += stride) {
    int d = dst[i];
    atomicAdd(&degw[d], ew[i]);
    atomicAdd(&cnt[d], 1);
  }
}

__global__ void dinv_kernel(float* __restrict__ degw) {
  int i = blockIdx.x * blockDim.x + threadIdx.x;
  if (i < NN) {
    float v = degw[i];
    degw[i] = (v > 0.f) ? rsqrtf(v) : 0.f;
  }
}

// ---------------- prefix scan for CSR row_ptr ----------------

__global__ void scan_p1(const int* __restrict__ cnt, int* __restrict__ bsum) {
  __shared__ int s[256];
  int b = blockIdx.x;
  int i = b * 256 + threadIdx.x;
  s[threadIdx.x] = (i < NN) ? cnt[i] : 0;
  __syncthreads();
  for (int off = 128; off; off >>= 1) {
    if (threadIdx.x < off) s[threadIdx.x] += s[threadIdx.x + off];
    __syncthreads();
  }
  if (threadIdx.x == 0) bsum[b] = s[0];
}

__global__ void scan_p2(int* __restrict__ bsum, int nb) {
  if (threadIdx.x == 0 && blockIdx.x == 0) {
    int run = 0;
    for (int b = 0; b < nb; ++b) { int t = bsum[b]; bsum[b] = run; run += t; }
  }
}

__global__ void scan_p3(const int* __restrict__ cnt, const int* __restrict__ bsum,
                        int* __restrict__ row_ptr) {
  __shared__ int s[256];
  int b = blockIdx.x;
  int i = b * 256 + threadIdx.x;
  s[threadIdx.x] = (i < NN) ? cnt[i] : 0;
  __syncthreads();
  for (int off = 1; off < 256; off <<= 1) {
    int t = (threadIdx.x >= off) ? s[threadIdx.x - off] : 0;
    __syncthreads();
    s[threadIdx.x] += t;
    __syncthreads();
  }
  if (i < NN) row_ptr[i + 1] = bsum[b] + s[threadIdx.x];
  if (i == 0) row_ptr[0] = 0;
}

__global__ void csr_fill(const int* __restrict__ src, const int* __restrict__ dst,
                         const float* __restrict__ ew, const float* __restrict__ dinv,
                         int* __restrict__ cursor, int* __restrict__ csrc,
                         float* __restrict__ cnorm) {
  int i = blockIdx.x * blockDim.x + threadIdx.x;
  int stride = gridDim.x * blockDim.x;
  for (; i < NE; i += stride) {
    int s = src[i], d = dst[i];
    float nm = dinv[s] * ew[i] * dinv[d];
    int p = atomicAdd(&cursor[d], 1);
    csrc[p] = s;
    cnorm[p] = nm;
  }
}

// ---------------- propagation layers ----------------
template <int MODE>
__global__ __launch_bounds__(256) void layer_kernel(
    const int* __restrict__ row_ptr, const int* __restrict__ csrc,
    const float* __restrict__ cnorm, const float* __restrict__ xsrc,
    const float* __restrict__ uemb, const float* __restrict__ iemb,
    float* __restrict__ y, float* __restrict__ OUT) {
  int wv = threadIdx.x >> 6, lane = threadIdx.x & 63;
  int n = blockIdx.x * 4 + wv;
  if (n >= NN) return;
  int beg = row_ptr[n], end = row_ptr[n + 1];
  float a0 = 0.f, a1 = 0.f;
  int j = beg;
  for (; j + 2 <= end; j += 2) {
    int s0 = csrc[j], s1 = csrc[j + 1];
    float w0 = cnorm[j], w1 = cnorm[j + 1];
    const float *x0p, *x1p;
    if (MODE == 0) {
      x0p = (s0 < NU) ? (uemb + (size_t)s0 * D) : (iemb + (size_t)(s0 - NU) * D);
      x1p = (s1 < NU) ? (uemb + (size_t)s1 * D) : (iemb + (size_t)(s1 - NU) * D);
    } else {
      x0p = xsrc + (size_t)s0 * D;
      x1p = xsrc + (size_t)s1 * D;
    }
    float v00 = x0p[lane], v01 = x0p[lane + 64];
    float v10 = x1p[lane], v11 = x1p[lane + 64];
    a0 = fmaf(w0, v00, a0); a1 = fmaf(w0, v01, a1);
    a0 = fmaf(w1, v10, a0); a1 = fmaf(w1, v11, a1);
  }
  if (j < end) {
    int s0 = csrc[j];
    float w0 = cnorm[j];
    const float* x0p;
    if (MODE == 0)
      x0p = (s0 < NU) ? (uemb + (size_t)s0 * D) : (iemb + (size_t)(s0 - NU) * D);
    else
      x0p = xsrc + (size_t)s0 * D;
    a0 = fmaf(w0, x0p[lane], a0);
    a1 = fmaf(w0, x0p[lane + 64], a1);
  }
  size_t o = (size_t)n * D + lane;
  if (MODE == 0) {
    float x00, x01;
    if (n < NU) { x00 = uemb[o]; x01 = uemb[o + 64]; }
    else        { x00 = iemb[o - (size_t)NU * D]; x01 = iemb[o + 64 - (size_t)NU * D]; }
    y[o] = a0; y[o + 64] = a1;
    OUT[o] = x00 + a0; OUT[o + 64] = x01 + a1;
  } else if (MODE == 1) {
    y[o] = a0; y[o + 64] = a1;
    OUT[o] += a0; OUT[o + 64] += a1;
  } else {
    OUT[o] = (OUT[o] + a0) * 0.25f;
    OUT[o + 64] = (OUT[o + 64] + a1) * 0.25f;
  }
}

// ---------------- W fp32 -> bf16 preconvert ----------------
__global__ void wconv_kernel(const float* __restrict__ W, unsigned short* __restrict__ Wb) {
  int i = blockIdx.x * blockDim.x + threadIdx.x;
  if (i < D * CD) Wb[i] = f2bf(W[i]);
}

// ---------------- content projection + align MSE (bf16 MFMA, fused) ----------------
// C[i][d] = sum_k content[i][k] * W[d][k]; both operands K-major ("B^T" shape).
// Block: 64 items x 128 D, BK=64, 4 waves; wave w owns col-tiles {2w,2w+1}.
__global__ __launch_bounds__(256) void align_mfma_kernel(
    const float* __restrict__ content, const unsigned short* __restrict__ Wb,
    const float* __restrict__ ifinal, float* __restrict__ accums) {
  __shared__ unsigned short Asm[64 * 64];    // [row][64k] bf16, XOR-swizzled
  __shared__ unsigned short Bsm[128 * 64];   // [row][64k] bf16, XOR-swizzled
  __shared__ float wred[4];

  int tid = threadIdx.x;
  int w = tid >> 6, lane = tid & 63;
  int i0 = blockIdx.x * 64;
  int lrow = lane & 15, kq = lane >> 4;

  f32x4 acc[4][2];
#pragma unroll
  for (int rt = 0; rt < 4; ++rt)
#pragma unroll
    for (int ct = 0; ct < 2; ++ct) acc[rt][ct] = (f32x4){0.f, 0.f, 0.f, 0.f};

  int ar = tid & 63, akc = tid >> 6;       // A staging: row, k-chunk(16 floats)
  int br = tid & 127, bh = tid >> 7;       // B staging: row, half(32 bf16)
  int arow_g = (i0 + ar < NI) ? (i0 + ar) : (NI - 1);
  const float* aG = content + (size_t)arow_g * CD + akc * 16;
  const unsigned short* bG = Wb + (size_t)br * CD + bh * 32;
  char* aL = (char*)Asm + ar * 128;
  int aswz = (ar & 7) << 4;
  char* bL = (char*)Bsm + br * 128;
  int bswz = (br & 7) << 4;

  for (int k0 = 0; k0 < CD; k0 += 64) {
    // ---- stage A: fp32 load + convert to bf16 ----
    unsigned short tmp[16];
#pragma unroll
    for (int q4 = 0; q4 < 4; ++q4) {
      float4 v = *(const float4*)(aG + k0 + q4 * 4);
      tmp[q4 * 4 + 0] = f2bf(v.x); tmp[q4 * 4 + 1] = f2bf(v.y);
      tmp[q4 * 4 + 2] = f2bf(v.z); tmp[q4 * 4 + 3] = f2bf(v.w);
    }
    *(uint4*)(aL + ((akc * 32) ^ aswz)) = *(uint4*)(tmp);
    *(uint4*)(aL + ((akc * 32 + 16) ^ aswz)) = *(uint4*)(tmp + 8);
    // ---- stage B: bf16 direct ----
#pragma unroll
    for (int q = 0; q < 4; ++q) {
      uint4 v = *(const uint4*)(bG + k0 + q * 8);
      *(uint4*)(bL + ((bh * 64 + q * 16) ^ bswz)) = v;
    }
    __syncthreads();
    // ---- MFMA ----
#pragma unroll
    for (int ks = 0; ks < 2; ++ks) {
      int kbyte = ks * 64 + kq * 16;
      bf16x8 af[4], bfr[2];
#pragma unroll
      for (int rt = 0; rt < 4; ++rt) {
        int row = rt * 16 + lrow;
        af[rt] = *(const bf16x8*)((char*)Asm + row * 128 + (kbyte ^ ((row & 7) << 4)));
      }
#pragma unroll
      for (int ct = 0; ct < 2; ++ct) {
        int row = w * 32 + ct * 16 + lrow;
        bfr[ct] = *(const bf16x8*)((char*)Bsm + row * 128 + (kbyte ^ ((row & 7) << 4)));
      }
#pragma unroll
      for (int rt = 0; rt < 4; ++rt)
#pragma unroll
        for (int ct = 0; ct < 2; ++ct)
          acc[rt][ct] = __builtin_amdgcn_mfma_f32_16x16x32_bf16(af[rt], bfr[ct], acc[rt][ct], 0, 0, 0);
    }
    __syncthreads();
  }

  // ---- fused MSE epilogue ----
  // C/D layout: col = lane&15, row = (lane>>4)*4 + reg
  float s = 0.f;
#pragma unroll
  for (int rt = 0; rt < 4; ++rt) {
#pragma unroll
    for (int j = 0; j < 4; ++j) {
      int it = i0 + rt * 16 + kq * 4 + j;
      if (it < NI) {
        int dcol0 = w * 32 + lrow;
        float r0 = ifinal[(size_t)it * D + dcol0];
        float r1 = ifinal[(size_t)it * D + dcol0 + 16];
        float d0 = r0 - acc[rt][0][j];
        float d1 = r1 - acc[rt][1][j];
        s = fmaf(d0, d0, s);
        s = fmaf(d1, d1, s);
      }
    }
  }
  for (int off = 32; off; off >>= 1) s += __shfl_down(s, off);
  if (lane == 0) wred[w] = s;
  __syncthreads();
  if (tid == 0) atomicAdd(&accums[2], wred[0] + wred[1] + wred[2] + wred[3]);
}

// ---------------- BPR + reg loss over batch ----------------
__global__ __launch_bounds__(256) void loss_batch(
    const int* __restrict__ bu, const int* __restrict__ bp, const int* __restrict__ bn,
    const float* __restrict__ OUT, float* __restrict__ accums) {
  int wv = threadIdx.x >> 6, lane = threadIdx.x & 63;
  int b = blockIdx.x * 4 + wv;
  if (b >= BATCH) return;
  const float* u = OUT + (size_t)bu[b] * D;
  const float* ip = OUT + ((size_t)NU + bp[b]) * D;
  const float* in_ = OUT + ((size_t)NU + bn[b]) * D;
  float u0 = u[lane], u1 = u[lane + 64];
  float p0 = ip[lane], p1 = ip[lane + 64];
  float n0 = in_[lane], n1 = in_[lane + 64];
  float ps = u0 * p0 + u1 * p1;
  float ns = u0 * n0 + u1 * n1;
  float rg = u0 * u0 + u1 * u1 + p0 * p0 + p1 * p1 + n0 * n0 + n1 * n1;
  for (int off = 32; off; off >>= 1) {
    ps += __shfl_down(ps, off);
    ns += __shfl_down(ns, off);
    rg += __shfl_down(rg, off);
  }
  if (lane == 0) {
    float x = ns - ps;
    float sp = fmaxf(x, 0.f) + log1pf(expf(-fabsf(x)));
    atomicAdd(&accums[0], sp);
    atomicAdd(&accums[1], rg);
  }
}

__global__ void finalize_kernel(const float* __restrict__ accums, float* __restrict__ out0) {
  if (threadIdx.x == 0 && blockIdx.x == 0) {
    float bpr = accums[0] / (float)BATCH;
    float reg = (accums[1] / (float)BATCH) * 1e-4f;
    float align = accums[2] / (float)((size_t)NI * D);
    out0[0] = bpr + reg + 0.1f * align;
  }
}

// ---------------- launch ----------------
extern "C" void kernel_launch(void* const* d_in, const int* in_sizes, int n_in,
                              void* d_out, int out_size, void* d_ws, size_t ws_size,
                              hipStream_t stream) {
  const int* edge_index = (const int*)d_in[0];
  const float* ew = (const float*)d_in[1];
  const int* bu = (const int*)d_in[2];
  const int* bp = (const int*)d_in[3];
  const int* bn = (const int*)d_in[4];
  const float* content = (const float*)d_in[5];
  const float* uemb = (const float*)d_in[6];
  const float* iemb = (const float*)d_in[7];
  const float* W = (const float*)d_in[8];
  const int* src = edge_index;
  const int* dst = edge_index + NE;
  float* outf = (float*)d_out;
  float* OUT = outf + 1;  // [NN][D], users then items (4B-aligned only!)

  char* ws = (char*)d_ws;
  size_t off = 0;
  auto alloc = [&](size_t bytes) {
    void* p = ws + off;
    off = alignup(off + bytes, 256);
    return p;
  };
  float* bufA = (float*)alloc((size_t)NN * D * 4);
  float* bufB = (float*)alloc((size_t)NN * D * 4);
  float* degw = (float*)alloc((size_t)NN * 4);
  int* cnt = (int*)alloc((size_t)NN * 4);
  int* row_ptr = (int*)alloc((size_t)(NN + 1) * 4);
  int* cursor = (int*)alloc((size_t)NN * 4);
  int NB = (NN + 255) / 256;
  int* bsum = (int*)alloc((size_t)NB * 4);
  int* csrc = (int*)alloc((size_t)NE * 4);
  float* cnorm = (float*)alloc((size_t)NE * 4);
  unsigned short* Wb = (unsigned short*)alloc((size_t)D * CD * 2);
  float* accums = (float*)alloc(16);

  hipMemsetAsync(degw, 0, (size_t)NN * 4, stream);
  hipMemsetAsync(cnt, 0, (size_t)NN * 4, stream);
  hipMemsetAsync(accums, 0, 16, stream);

  deg_count_kernel<<<2048, 256, 0, stream>>>(dst, ew, degw, cnt);
  dinv_kernel<<<(NN + 255) / 256, 256, 0, stream>>>(degw);
  scan_p1<<<NB, 256, 0, stream>>>(cnt, bsum);
  scan_p2<<<1, 64, 0, stream>>>(bsum, NB);
  scan_p3<<<NB, 256, 0, stream>>>(cnt, bsum, row_ptr);
  hipMemcpyAsync(cursor, row_ptr, (size_t)NN * 4, hipMemcpyDeviceToDevice, stream);
  csr_fill<<<2048, 256, 0, stream>>>(src, dst, ew, degw, cursor, csrc, cnorm);
  wconv_kernel<<<(D * CD + 255) / 256, 256, 0, stream>>>(W, Wb);

  int LB = (NN + 3) / 4;
  layer_kernel<0><<<LB, 256, 0, stream>>>(row_ptr, csrc, cnorm, nullptr, uemb, iemb, bufA, OUT);
  layer_kernel<1><<<LB, 256, 0, stream>>>(row_ptr, csrc, cnorm, bufA, uemb, iemb, bufB, OUT);
  layer_kernel<2><<<LB, 256, 0, stream>>>(row_ptr, csrc, cnorm, bufB, uemb, iemb, nullptr, OUT);

  align_mfma_kernel<<<(NI + 63) / 64, 256, 0, stream>>>(content, Wb, OUT + (size_t)NU * D, accums);
  loss_batch<<<(BATCH + 3) / 4, 256, 0, stream>>>(bu, bp, bn, OUT, accums);
  finalize_kernel<<<1, 64, 0, stream>>>(accums, outf);
}

// Round 3
// 618.869 us; speedup vs baseline: 1.5005x; 1.2131x over previous
//
#include <hip/hip_runtime.h>
#include <math.h>

#define NU 100000
#define NI 50000
#define NN 150000
#define D 128
#define NE 1000000
#define CD 768
#define BATCH 4096

typedef short bf16x8 __attribute__((ext_vector_type(8)));
typedef float f32x4 __attribute__((ext_vector_type(4)));

static inline size_t alignup(size_t x, size_t a) { return (x + a - 1) / a * a; }

__device__ inline unsigned short f2bf(float f) {
  unsigned int u = __builtin_bit_cast(unsigned int, f);
  unsigned int r = (u + 0x7fffu + ((u >> 16) & 1u)) >> 16;
  return (unsigned short)r;
}
__device__ inline unsigned int pack2bf(float lo, float hi) {
  return (unsigned int)f2bf(lo) | ((unsigned int)f2bf(hi) << 16);
}
__device__ inline float bflo(unsigned int p) {
  return __builtin_bit_cast(float, p << 16);
}
__device__ inline float bfhi(unsigned int p) {
  return __builtin_bit_cast(float, p & 0xffff0000u);
}

// ---------------- degree / normalization ----------------

__global__ void deg_count_kernel(const int* __restrict__ dst, const float* __restrict__ ew,
                                 float* __restrict__ degw, int* __restrict__ cnt) {
  int i = blockIdx.x * blockDim.x + threadIdx.x;
  int stride = gridDim.x * blockDim.x;
  for (; i < NE; i += stride) {
    int d = dst[i];
    atomicAdd(&degw[d], ew[i]);
    atomicAdd(&cnt[d], 1);
  }
}

__global__ void dinv_kernel(float* __restrict__ degw) {
  int i = blockIdx.x * blockDim.x + threadIdx.x;
  if (i < NN) {
    float v = degw[i];
    degw[i] = (v > 0.f) ? rsqrtf(v) : 0.f;
  }
}

// ---------------- prefix scan for CSR row_ptr ----------------

__global__ void scan_p1(const int* __restrict__ cnt, int* __restrict__ bsum) {
  __shared__ int s[256];
  int b = blockIdx.x;
  int i = b * 256 + threadIdx.x;
  s[threadIdx.x] = (i < NN) ? cnt[i] : 0;
  __syncthreads();
  for (int off = 128; off; off >>= 1) {
    if (threadIdx.x < off) s[threadIdx.x] += s[threadIdx.x + off];
    __syncthreads();
  }
  if (threadIdx.x == 0) bsum[b] = s[0];
}

// single-block parallel exclusive scan over nb<=1024 block sums
__global__ __launch_bounds__(1024) void scan_p2(int* __restrict__ bsum, int nb) {
  __shared__ int s[1024];
  int t = threadIdx.x;
  int v = (t < nb) ? bsum[t] : 0;
  s[t] = v;
  __syncthreads();
  for (int off = 1; off < 1024; off <<= 1) {
    int u = (t >= off) ? s[t - off] : 0;
    __syncthreads();
    s[t] += u;
    __syncthreads();
  }
  if (t < nb) bsum[t] = s[t] - v;
}

__global__ void scan_p3(const int* __restrict__ cnt, const int* __restrict__ bsum,
                        int* __restrict__ row_ptr) {
  __shared__ int s[256];
  int b = blockIdx.x;
  int i = b * 256 + threadIdx.x;
  s[threadIdx.x] = (i < NN) ? cnt[i] : 0;
  __syncthreads();
  for (int off = 1; off < 256; off <<= 1) {
    int t = (threadIdx.x >= off) ? s[threadIdx.x - off] : 0;
    __syncthreads();
    s[threadIdx.x] += t;
    __syncthreads();
  }
  if (i < NN) row_ptr[i + 1] = bsum[b] + s[threadIdx.x];
  if (i == 0) row_ptr[0] = 0;
}

__global__ void csr_fill(const int* __restrict__ src, const int* __restrict__ dst,
                         const float* __restrict__ ew, const float* __restrict__ dinv,
                         int* __restrict__ cursor, int* __restrict__ csrc,
                         float* __restrict__ cnorm) {
  int i = blockIdx.x * blockDim.x + threadIdx.x;
  int stride = gridDim.x * blockDim.x;
  for (; i < NE; i += stride) {
    int s = src[i], d = dst[i];
    float nm = dinv[s] * ew[i] * dinv[d];
    int p = atomicAdd(&cursor[d], 1);
    csrc[p] = s;
    cnorm[p] = nm;
  }
}

// ---------------- x0 conversion: concat(uemb,iemb) -> bf16 ----------------
// 8 floats per thread: 2x float4 in, 1x uint4 out
__global__ void xconv_kernel(const float* __restrict__ uemb, const float* __restrict__ iemb,
                             unsigned int* __restrict__ x0b) {
  size_t t = (size_t)blockIdx.x * blockDim.x + threadIdx.x;
  size_t total = (size_t)NN * D / 8;
  if (t >= total) return;
  size_t f = t * 8;
  const float* p = (f < (size_t)NU * D) ? (uemb + f) : (iemb + (f - (size_t)NU * D));
  float4 a = *(const float4*)p;
  float4 b = *(const float4*)(p + 4);
  uint4 o;
  o.x = pack2bf(a.x, a.y);
  o.y = pack2bf(a.z, a.w);
  o.z = pack2bf(b.x, b.y);
  o.w = pack2bf(b.z, b.w);
  *(uint4*)(x0b + t * 4) = o;
}

// ---------------- propagation layers (bf16 state) ----------------
// wave per node; lane owns dims {2*lane, 2*lane+1} via one u32 (bf16x2)
__global__ __launch_bounds__(256) void gather_kernel(
    const int* __restrict__ row_ptr, const int* __restrict__ csrc,
    const float* __restrict__ cnorm, const unsigned int* __restrict__ xin,
    unsigned int* __restrict__ yout) {
  int wv = threadIdx.x >> 6, lane = threadIdx.x & 63;
  int n = blockIdx.x * 4 + wv;
  if (n >= NN) return;
  int beg = row_ptr[n], end = row_ptr[n + 1];
  float a0 = 0.f, a1 = 0.f;
  int j = beg;
  for (; j + 2 <= end; j += 2) {
    int s0 = csrc[j], s1 = csrc[j + 1];
    float w0 = cnorm[j], w1 = cnorm[j + 1];
    unsigned int p0 = xin[(size_t)s0 * 64 + lane];
    unsigned int p1 = xin[(size_t)s1 * 64 + lane];
    a0 = fmaf(w0, bflo(p0), a0); a1 = fmaf(w0, bfhi(p0), a1);
    a0 = fmaf(w1, bflo(p1), a0); a1 = fmaf(w1, bfhi(p1), a1);
  }
  if (j < end) {
    int s0 = csrc[j];
    float w0 = cnorm[j];
    unsigned int p0 = xin[(size_t)s0 * 64 + lane];
    a0 = fmaf(w0, bflo(p0), a0); a1 = fmaf(w0, bfhi(p0), a1);
  }
  yout[(size_t)n * 64 + lane] = pack2bf(a0, a1);
}

// final layer: gather y3 from y2b, then OUT = 0.25*(x0+y1+y2+y3) in fp32
__global__ __launch_bounds__(256) void final_kernel(
    const int* __restrict__ row_ptr, const int* __restrict__ csrc,
    const float* __restrict__ cnorm, const unsigned int* __restrict__ x0b,
    const unsigned int* __restrict__ y1b, const unsigned int* __restrict__ y2b,
    float* __restrict__ OUT) {
  int wv = threadIdx.x >> 6, lane = threadIdx.x & 63;
  int n = blockIdx.x * 4 + wv;
  if (n >= NN) return;
  int beg = row_ptr[n], end = row_ptr[n + 1];
  float a0 = 0.f, a1 = 0.f;
  int j = beg;
  for (; j + 2 <= end; j += 2) {
    int s0 = csrc[j], s1 = csrc[j + 1];
    float w0 = cnorm[j], w1 = cnorm[j + 1];
    unsigned int p0 = y2b[(size_t)s0 * 64 + lane];
    unsigned int p1 = y2b[(size_t)s1 * 64 + lane];
    a0 = fmaf(w0, bflo(p0), a0); a1 = fmaf(w0, bfhi(p0), a1);
    a0 = fmaf(w1, bflo(p1), a0); a1 = fmaf(w1, bfhi(p1), a1);
  }
  if (j < end) {
    int s0 = csrc[j];
    float w0 = cnorm[j];
    unsigned int p0 = y2b[(size_t)s0 * 64 + lane];
    a0 = fmaf(w0, bflo(p0), a0); a1 = fmaf(w0, bfhi(p0), a1);
  }
  size_t r = (size_t)n * 64 + lane;
  unsigned int q0 = x0b[r], q1 = y1b[r], q2 = y2b[r];
  float s0f = bflo(q0) + bflo(q1) + bflo(q2) + a0;
  float s1f = bfhi(q0) + bfhi(q1) + bfhi(q2) + a1;
  size_t o = (size_t)n * D + lane * 2;
  OUT[o] = s0f * 0.25f;
  OUT[o + 1] = s1f * 0.25f;
}

// ---------------- W fp32 -> bf16 preconvert ----------------
__global__ void wconv_kernel(const float* __restrict__ W, unsigned short* __restrict__ Wb) {
  int i = blockIdx.x * blockDim.x + threadIdx.x;
  if (i < D * CD) Wb[i] = f2bf(W[i]);
}

// ---------------- content projection + align MSE (bf16 MFMA, fused) ----------------
__global__ __launch_bounds__(256) void align_mfma_kernel(
    const float* __restrict__ content, const unsigned short* __restrict__ Wb,
    const float* __restrict__ ifinal, float* __restrict__ accums) {
  __shared__ unsigned short Asm[64 * 64];
  __shared__ unsigned short Bsm[128 * 64];
  __shared__ float wred[4];

  int tid = threadIdx.x;
  int w = tid >> 6, lane = tid & 63;
  int i0 = blockIdx.x * 64;
  int lrow = lane & 15, kq = lane >> 4;

  f32x4 acc[4][2];
#pragma unroll
  for (int rt = 0; rt < 4; ++rt)
#pragma unroll
    for (int ct = 0; ct < 2; ++ct) acc[rt][ct] = (f32x4){0.f, 0.f, 0.f, 0.f};

  int ar = tid & 63, akc = tid >> 6;
  int br = tid & 127, bh = tid >> 7;
  int arow_g = (i0 + ar < NI) ? (i0 + ar) : (NI - 1);
  const float* aG = content + (size_t)arow_g * CD + akc * 16;
  const unsigned short* bG = Wb + (size_t)br * CD + bh * 32;
  char* aL = (char*)Asm + ar * 128;
  int aswz = (ar & 7) << 4;
  char* bL = (char*)Bsm + br * 128;
  int bswz = (br & 7) << 4;

  for (int k0 = 0; k0 < CD; k0 += 64) {
    unsigned short tmp[16];
#pragma unroll
    for (int q4 = 0; q4 < 4; ++q4) {
      float4 v = *(const float4*)(aG + k0 + q4 * 4);
      tmp[q4 * 4 + 0] = f2bf(v.x); tmp[q4 * 4 + 1] = f2bf(v.y);
      tmp[q4 * 4 + 2] = f2bf(v.z); tmp[q4 * 4 + 3] = f2bf(v.w);
    }
    *(uint4*)(aL + ((akc * 32) ^ aswz)) = *(uint4*)(tmp);
    *(uint4*)(aL + ((akc * 32 + 16) ^ aswz)) = *(uint4*)(tmp + 8);
#pragma unroll
    for (int q = 0; q < 4; ++q) {
      uint4 v = *(const uint4*)(bG + k0 + q * 8);
      *(uint4*)(bL + ((bh * 64 + q * 16) ^ bswz)) = v;
    }
    __syncthreads();
#pragma unroll
    for (int ks = 0; ks < 2; ++ks) {
      int kbyte = ks * 64 + kq * 16;
      bf16x8 af[4], bfr[2];
#pragma unroll
      for (int rt = 0; rt < 4; ++rt) {
        int row = rt * 16 + lrow;
        af[rt] = *(const bf16x8*)((char*)Asm + row * 128 + (kbyte ^ ((row & 7) << 4)));
      }
#pragma unroll
      for (int ct = 0; ct < 2; ++ct) {
        int row = w * 32 + ct * 16 + lrow;
        bfr[ct] = *(const bf16x8*)((char*)Bsm + row * 128 + (kbyte ^ ((row & 7) << 4)));
      }
#pragma unroll
      for (int rt = 0; rt < 4; ++rt)
#pragma unroll
        for (int ct = 0; ct < 2; ++ct)
          acc[rt][ct] = __builtin_amdgcn_mfma_f32_16x16x32_bf16(af[rt], bfr[ct], acc[rt][ct], 0, 0, 0);
    }
    __syncthreads();
  }

  float s = 0.f;
#pragma unroll
  for (int rt = 0; rt < 4; ++rt) {
#pragma unroll
    for (int j = 0; j < 4; ++j) {
      int it = i0 + rt * 16 + kq * 4 + j;
      if (it < NI) {
        int dcol0 = w * 32 + lrow;
        float r0 = ifinal[(size_t)it * D + dcol0];
        float r1 = ifinal[(size_t)it * D + dcol0 + 16];
        float d0 = r0 - acc[rt][0][j];
        float d1 = r1 - acc[rt][1][j];
        s = fmaf(d0, d0, s);
        s = fmaf(d1, d1, s);
      }
    }
  }
  for (int off = 32; off; off >>= 1) s += __shfl_down(s, off);
  if (lane == 0) wred[w] = s;
  __syncthreads();
  if (tid == 0) atomicAdd(&accums[2], wred[0] + wred[1] + wred[2] + wred[3]);
}

// ---------------- BPR + reg loss over batch ----------------
__global__ __launch_bounds__(256) void loss_batch(
    const int* __restrict__ bu, const int* __restrict__ bp, const int* __restrict__ bn,
    const float* __restrict__ OUT, float* __restrict__ accums) {
  int wv = threadIdx.x >> 6, lane = threadIdx.x & 63;
  int b = blockIdx.x * 4 + wv;
  if (b >= BATCH) return;
  const float* u = OUT + (size_t)bu[b] * D;
  const float* ip = OUT + ((size_t)NU + bp[b]) * D;
  const float* in_ = OUT + ((size_t)NU + bn[b]) * D;
  float u0 = u[lane], u1 = u[lane + 64];
  float p0 = ip[lane], p1 = ip[lane + 64];
  float n0 = in_[lane], n1 = in_[lane + 64];
  float ps = u0 * p0 + u1 * p1;
  float ns = u0 * n0 + u1 * n1;
  float rg = u0 * u0 + u1 * u1 + p0 * p0 + p1 * p1 + n0 * n0 + n1 * n1;
  for (int off = 32; off; off >>= 1) {
    ps += __shfl_down(ps, off);
    ns += __shfl_down(ns, off);
    rg += __shfl_down(rg, off);
  }
  if (lane == 0) {
    float x = ns - ps;
    float sp = fmaxf(x, 0.f) + log1pf(expf(-fabsf(x)));
    atomicAdd(&accums[0], sp);
    atomicAdd(&accums[1], rg);
  }
}

__global__ void finalize_kernel(const float* __restrict__ accums, float* __restrict__ out0) {
  if (threadIdx.x == 0 && blockIdx.x == 0) {
    float bpr = accums[0] / (float)BATCH;
    float reg = (accums[1] / (float)BATCH) * 1e-4f;
    float align = accums[2] / (float)((size_t)NI * D);
    out0[0] = bpr + reg + 0.1f * align;
  }
}

// ---------------- launch ----------------
extern "C" void kernel_launch(void* const* d_in, const int* in_sizes, int n_in,
                              void* d_out, int out_size, void* d_ws, size_t ws_size,
                              hipStream_t stream) {
  const int* edge_index = (const int*)d_in[0];
  const float* ew = (const float*)d_in[1];
  const int* bu = (const int*)d_in[2];
  const int* bp = (const int*)d_in[3];
  const int* bn = (const int*)d_in[4];
  const float* content = (const float*)d_in[5];
  const float* uemb = (const float*)d_in[6];
  const float* iemb = (const float*)d_in[7];
  const float* W = (const float*)d_in[8];
  const int* src = edge_index;
  const int* dst = edge_index + NE;
  float* outf = (float*)d_out;
  float* OUT = outf + 1;  // [NN][D] fp32 (4B-aligned only!)

  char* ws = (char*)d_ws;
  size_t off = 0;
  auto alloc = [&](size_t bytes) {
    void* p = ws + off;
    off = alignup(off + bytes, 256);
    return p;
  };
  unsigned int* x0b = (unsigned int*)alloc((size_t)NN * 64 * 4);
  unsigned int* y1b = (unsigned int*)alloc((size_t)NN * 64 * 4);
  unsigned int* y2b = (unsigned int*)alloc((size_t)NN * 64 * 4);
  float* degw = (float*)alloc((size_t)NN * 4);
  int* cnt = (int*)alloc((size_t)NN * 4);
  int* row_ptr = (int*)alloc((size_t)(NN + 1) * 4);
  int* cursor = (int*)alloc((size_t)NN * 4);
  int NB = (NN + 255) / 256;
  int* bsum = (int*)alloc((size_t)NB * 4);
  int* csrc = (int*)alloc((size_t)NE * 4);
  float* cnorm = (float*)alloc((size_t)NE * 4);
  unsigned short* Wb = (unsigned short*)alloc((size_t)D * CD * 2);
  float* accums = (float*)alloc(16);

  hipMemsetAsync(degw, 0, (size_t)NN * 4, stream);
  hipMemsetAsync(cnt, 0, (size_t)NN * 4, stream);
  hipMemsetAsync(accums, 0, 16, stream);

  deg_count_kernel<<<2048, 256, 0, stream>>>(dst, ew, degw, cnt);
  dinv_kernel<<<(NN + 255) / 256, 256, 0, stream>>>(degw);
  scan_p1<<<NB, 256, 0, stream>>>(cnt, bsum);
  scan_p2<<<1, 1024, 0, stream>>>(bsum, NB);
  scan_p3<<<NB, 256, 0, stream>>>(cnt, bsum, row_ptr);
  hipMemcpyAsync(cursor, row_ptr, (size_t)NN * 4, hipMemcpyDeviceToDevice, stream);
  csr_fill<<<2048, 256, 0, stream>>>(src, dst, ew, degw, cursor, csrc, cnorm);
  xconv_kernel<<<(NN * D / 8 + 255) / 256, 256, 0, stream>>>(uemb, iemb, x0b);
  wconv_kernel<<<(D * CD + 255) / 256, 256, 0, stream>>>(W, Wb);

  int LB = (NN + 3) / 4;
  gather_kernel<<<LB, 256, 0, stream>>>(row_ptr, csrc, cnorm, x0b, y1b);
  gather_kernel<<<LB, 256, 0, stream>>>(row_ptr, csrc, cnorm, y1b, y2b);
  final_kernel<<<LB, 256, 0, stream>>>(row_ptr, csrc, cnorm, x0b, y1b, y2b, OUT);

  align_mfma_kernel<<<(NI + 63) / 64, 256, 0, stream>>>(content, Wb, OUT + (size_t)NU * D, accums);
  loss_batch<<<(BATCH + 3) / 4, 256, 0, stream>>>(bu, bp, bn, OUT, accums);
  finalize_kernel<<<1, 64, 0, stream>>>(accums, outf);
}

// Round 4
// 540.374 us; speedup vs baseline: 1.7184x; 1.1453x over previous
//
#include <hip/hip_runtime.h>
#include <math.h>

#define NU 100000
#define NI 50000
#define NN 150000
#define D 128
#define NE 1000000
#define CD 768
#define BATCH 4096

typedef short bf16x8 __attribute__((ext_vector_type(8)));
typedef float f32x4 __attribute__((ext_vector_type(4)));

static inline size_t alignup(size_t x, size_t a) { return (x + a - 1) / a * a; }

__device__ inline unsigned short f2bf(float f) {
  unsigned int u = __builtin_bit_cast(unsigned int, f);
  unsigned int r = (u + 0x7fffu + ((u >> 16) & 1u)) >> 16;
  return (unsigned short)r;
}
__device__ inline unsigned int pack2bf(float lo, float hi) {
  return (unsigned int)f2bf(lo) | ((unsigned int)f2bf(hi) << 16);
}
__device__ inline float bflo(unsigned int p) {
  return __builtin_bit_cast(float, p << 16);
}
__device__ inline float bfhi(unsigned int p) {
  return __builtin_bit_cast(float, p & 0xffff0000u);
}

// ---------------- degree / normalization ----------------

__global__ void deg_count_kernel(const int* __restrict__ dst, const float* __restrict__ ew,
                                 float* __restrict__ degw, int* __restrict__ cnt) {
  int i = blockIdx.x * blockDim.x + threadIdx.x;
  int stride = gridDim.x * blockDim.x;
  for (; i < NE; i += stride) {
    int d = dst[i];
    atomicAdd(&degw[d], ew[i]);
    atomicAdd(&cnt[d], 1);
  }
}

__global__ void dinv_kernel(float* __restrict__ degw) {
  int i = blockIdx.x * blockDim.x + threadIdx.x;
  if (i < NN) {
    float v = degw[i];
    degw[i] = (v > 0.f) ? rsqrtf(v) : 0.f;
  }
}

// ---------------- prefix scan for CSR row_ptr ----------------

__global__ void scan_p1(const int* __restrict__ cnt, int* __restrict__ bsum) {
  __shared__ int s[256];
  int b = blockIdx.x;
  int i = b * 256 + threadIdx.x;
  s[threadIdx.x] = (i < NN) ? cnt[i] : 0;
  __syncthreads();
  for (int off = 128; off; off >>= 1) {
    if (threadIdx.x < off) s[threadIdx.x] += s[threadIdx.x + off];
    __syncthreads();
  }
  if (threadIdx.x == 0) bsum[b] = s[0];
}

// single-block parallel exclusive scan over nb<=1024 block sums
__global__ __launch_bounds__(1024) void scan_p2(int* __restrict__ bsum, int nb) {
  __shared__ int s[1024];
  int t = threadIdx.x;
  int v = (t < nb) ? bsum[t] : 0;
  s[t] = v;
  __syncthreads();
  for (int off = 1; off < 1024; off <<= 1) {
    int u = (t >= off) ? s[t - off] : 0;
    __syncthreads();
    s[t] += u;
    __syncthreads();
  }
  if (t < nb) bsum[t] = s[t] - v;
}

__global__ void scan_p3(const int* __restrict__ cnt, const int* __restrict__ bsum,
                        int* __restrict__ row_ptr) {
  __shared__ int s[256];
  int b = blockIdx.x;
  int i = b * 256 + threadIdx.x;
  s[threadIdx.x] = (i < NN) ? cnt[i] : 0;
  __syncthreads();
  for (int off = 1; off < 256; off <<= 1) {
    int t = (threadIdx.x >= off) ? s[threadIdx.x - off] : 0;
    __syncthreads();
    s[threadIdx.x] += t;
    __syncthreads();
  }
  if (i < NN) row_ptr[i + 1] = bsum[b] + s[threadIdx.x];
  if (i == 0) row_ptr[0] = 0;
}

__global__ void csr_fill(const int* __restrict__ src, const int* __restrict__ dst,
                         const float* __restrict__ ew, const float* __restrict__ dinv,
                         int* __restrict__ cursor, int* __restrict__ csrc,
                         float* __restrict__ cnorm) {
  int i = blockIdx.x * blockDim.x + threadIdx.x;
  int stride = gridDim.x * blockDim.x;
  for (; i < NE; i += stride) {
    int s = src[i], d = dst[i];
    float nm = dinv[s] * ew[i] * dinv[d];
    int p = atomicAdd(&cursor[d], 1);
    csrc[p] = s;
    cnorm[p] = nm;
  }
}

// ---------------- x0 conversion: concat(uemb,iemb) -> bf16 ----------------
__global__ void xconv_kernel(const float* __restrict__ uemb, const float* __restrict__ iemb,
                             unsigned int* __restrict__ x0b) {
  size_t t = (size_t)blockIdx.x * blockDim.x + threadIdx.x;
  size_t total = (size_t)NN * D / 8;
  if (t >= total) return;
  size_t f = t * 8;
  const float* p = (f < (size_t)NU * D) ? (uemb + f) : (iemb + (f - (size_t)NU * D));
  float4 a = *(const float4*)p;
  float4 b = *(const float4*)(p + 4);
  uint4 o;
  o.x = pack2bf(a.x, a.y);
  o.y = pack2bf(a.z, a.w);
  o.z = pack2bf(b.x, b.y);
  o.w = pack2bf(b.z, b.w);
  *(uint4*)(x0b + t * 4) = o;
}

// ---------------- propagation layers (bf16 state) ----------------
__global__ __launch_bounds__(256) void gather_kernel(
    const int* __restrict__ row_ptr, const int* __restrict__ csrc,
    const float* __restrict__ cnorm, const unsigned int* __restrict__ xin,
    unsigned int* __restrict__ yout) {
  int wv = threadIdx.x >> 6, lane = threadIdx.x & 63;
  int n = blockIdx.x * 4 + wv;
  if (n >= NN) return;
  int beg = row_ptr[n], end = row_ptr[n + 1];
  float a0 = 0.f, a1 = 0.f;
  int j = beg;
  for (; j + 2 <= end; j += 2) {
    int s0 = csrc[j], s1 = csrc[j + 1];
    float w0 = cnorm[j], w1 = cnorm[j + 1];
    unsigned int p0 = xin[(size_t)s0 * 64 + lane];
    unsigned int p1 = xin[(size_t)s1 * 64 + lane];
    a0 = fmaf(w0, bflo(p0), a0); a1 = fmaf(w0, bfhi(p0), a1);
    a0 = fmaf(w1, bflo(p1), a0); a1 = fmaf(w1, bfhi(p1), a1);
  }
  if (j < end) {
    int s0 = csrc[j];
    float w0 = cnorm[j];
    unsigned int p0 = xin[(size_t)s0 * 64 + lane];
    a0 = fmaf(w0, bflo(p0), a0); a1 = fmaf(w0, bfhi(p0), a1);
  }
  yout[(size_t)n * 64 + lane] = pack2bf(a0, a1);
}

// final layer: gather y3 from y2b, then OUT = 0.25*(x0+y1+y2+y3) in fp32
__global__ __launch_bounds__(256) void final_kernel(
    const int* __restrict__ row_ptr, const int* __restrict__ csrc,
    const float* __restrict__ cnorm, const unsigned int* __restrict__ x0b,
    const unsigned int* __restrict__ y1b, const unsigned int* __restrict__ y2b,
    float* __restrict__ OUT) {
  int wv = threadIdx.x >> 6, lane = threadIdx.x & 63;
  int n = blockIdx.x * 4 + wv;
  if (n >= NN) return;
  int beg = row_ptr[n], end = row_ptr[n + 1];
  float a0 = 0.f, a1 = 0.f;
  int j = beg;
  for (; j + 2 <= end; j += 2) {
    int s0 = csrc[j], s1 = csrc[j + 1];
    float w0 = cnorm[j], w1 = cnorm[j + 1];
    unsigned int p0 = y2b[(size_t)s0 * 64 + lane];
    unsigned int p1 = y2b[(size_t)s1 * 64 + lane];
    a0 = fmaf(w0, bflo(p0), a0); a1 = fmaf(w0, bfhi(p0), a1);
    a0 = fmaf(w1, bflo(p1), a0); a1 = fmaf(w1, bfhi(p1), a1);
  }
  if (j < end) {
    int s0 = csrc[j];
    float w0 = cnorm[j];
    unsigned int p0 = y2b[(size_t)s0 * 64 + lane];
    a0 = fmaf(w0, bflo(p0), a0); a1 = fmaf(w0, bfhi(p0), a1);
  }
  size_t r = (size_t)n * 64 + lane;
  unsigned int q0 = x0b[r], q1 = y1b[r], q2 = y2b[r];
  float s0f = bflo(q0) + bflo(q1) + bflo(q2) + a0;
  float s1f = bfhi(q0) + bfhi(q1) + bfhi(q2) + a1;
  size_t o = (size_t)n * D + lane * 2;
  OUT[o] = s0f * 0.25f;
  OUT[o + 1] = s1f * 0.25f;
}

// ---------------- W fp32 -> bf16 preconvert ----------------
__global__ void wconv_kernel(const float* __restrict__ W, unsigned short* __restrict__ Wb) {
  int i = blockIdx.x * blockDim.x + threadIdx.x;
  if (i < D * CD) Wb[i] = f2bf(W[i]);
}

// ---------------- content projection + align MSE (bf16 MFMA, fused) ----------------
__global__ __launch_bounds__(256) void align_mfma_kernel(
    const float* __restrict__ content, const unsigned short* __restrict__ Wb,
    const float* __restrict__ ifinal, float* __restrict__ accums) {
  __shared__ unsigned short Asm[64 * 64];
  __shared__ unsigned short Bsm[128 * 64];
  __shared__ float wred[4];

  int tid = threadIdx.x;
  int w = tid >> 6, lane = tid & 63;
  int i0 = blockIdx.x * 64;
  int lrow = lane & 15, kq = lane >> 4;

  f32x4 acc[4][2];
#pragma unroll
  for (int rt = 0; rt < 4; ++rt)
#pragma unroll
    for (int ct = 0; ct < 2; ++ct) acc[rt][ct] = (f32x4){0.f, 0.f, 0.f, 0.f};

  int ar = tid & 63, akc = tid >> 6;
  int br = tid & 127, bh = tid >> 7;
  int arow_g = (i0 + ar < NI) ? (i0 + ar) : (NI - 1);
  const float* aG = content + (size_t)arow_g * CD + akc * 16;
  const unsigned short* bG = Wb + (size_t)br * CD + bh * 32;
  char* aL = (char*)Asm + ar * 128;
  int aswz = (ar & 7) << 4;
  char* bL = (char*)Bsm + br * 128;
  int bswz = (br & 7) << 4;

  for (int k0 = 0; k0 < CD; k0 += 64) {
    unsigned short tmp[16];
#pragma unroll
    for (int q4 = 0; q4 < 4; ++q4) {
      float4 v = *(const float4*)(aG + k0 + q4 * 4);
      tmp[q4 * 4 + 0] = f2bf(v.x); tmp[q4 * 4 + 1] = f2bf(v.y);
      tmp[q4 * 4 + 2] = f2bf(v.z); tmp[q4 * 4 + 3] = f2bf(v.w);
    }
    *(uint4*)(aL + ((akc * 32) ^ aswz)) = *(uint4*)(tmp);
    *(uint4*)(aL + ((akc * 32 + 16) ^ aswz)) = *(uint4*)(tmp + 8);
#pragma unroll
    for (int q = 0; q < 4; ++q) {
      uint4 v = *(const uint4*)(bG + k0 + q * 8);
      *(uint4*)(bL + ((bh * 64 + q * 16) ^ bswz)) = v;
    }
    __syncthreads();
#pragma unroll
    for (int ks = 0; ks < 2; ++ks) {
      int kbyte = ks * 64 + kq * 16;
      bf16x8 af[4], bfr[2];
#pragma unroll
      for (int rt = 0; rt < 4; ++rt) {
        int row = rt * 16 + lrow;
        af[rt] = *(const bf16x8*)((char*)Asm + row * 128 + (kbyte ^ ((row & 7) << 4)));
      }
#pragma unroll
      for (int ct = 0; ct < 2; ++ct) {
        int row = w * 32 + ct * 16 + lrow;
        bfr[ct] = *(const bf16x8*)((char*)Bsm + row * 128 + (kbyte ^ ((row & 7) << 4)));
      }
#pragma unroll
      for (int rt = 0; rt < 4; ++rt)
#pragma unroll
        for (int ct = 0; ct < 2; ++ct)
          acc[rt][ct] = __builtin_amdgcn_mfma_f32_16x16x32_bf16(af[rt], bfr[ct], acc[rt][ct], 0, 0, 0);
    }
    __syncthreads();
  }

  float s = 0.f;
#pragma unroll
  for (int rt = 0; rt < 4; ++rt) {
#pragma unroll
    for (int j = 0; j < 4; ++j) {
      int it = i0 + rt * 16 + kq * 4 + j;
      if (it < NI) {
        int dcol0 = w * 32 + lrow;
        float r0 = ifinal[(size_t)it * D + dcol0];
        float r1 = ifinal[(size_t)it * D + dcol0 + 16];
        float d0 = r0 - acc[rt][0][j];
        float d1 = r1 - acc[rt][1][j];
        s = fmaf(d0, d0, s);
        s = fmaf(d1, d1, s);
      }
    }
  }
  for (int off = 32; off; off >>= 1) s += __shfl_down(s, off);
  if (lane == 0) wred[w] = s;
  __syncthreads();
  if (tid == 0) atomicAdd(&accums[2], wred[0] + wred[1] + wred[2] + wred[3]);
}

// ---------------- BPR + reg loss over batch (block-reduced atomics) ----------------
__global__ __launch_bounds__(256) void loss_batch(
    const int* __restrict__ bu, const int* __restrict__ bp, const int* __restrict__ bn,
    const float* __restrict__ OUT, float* __restrict__ accums) {
  __shared__ float wsp[4], wrg[4];
  int wv = threadIdx.x >> 6, lane = threadIdx.x & 63;
  int gw = blockIdx.x * 4 + wv;        // global wave id
  int nw = gridDim.x * 4;
  float lsp = 0.f, lrg = 0.f;
  for (int b = gw; b < BATCH; b += nw) {
    const float* u = OUT + (size_t)bu[b] * D;
    const float* ip = OUT + ((size_t)NU + bp[b]) * D;
    const float* in_ = OUT + ((size_t)NU + bn[b]) * D;
    float u0 = u[lane], u1 = u[lane + 64];
    float p0 = ip[lane], p1 = ip[lane + 64];
    float n0 = in_[lane], n1 = in_[lane + 64];
    float ps = u0 * p0 + u1 * p1;
    float ns = u0 * n0 + u1 * n1;
    float rg = u0 * u0 + u1 * u1 + p0 * p0 + p1 * p1 + n0 * n0 + n1 * n1;
    for (int off = 32; off; off >>= 1) {
      ps += __shfl_down(ps, off);
      ns += __shfl_down(ns, off);
      rg += __shfl_down(rg, off);
    }
    if (lane == 0) {
      float x = ns - ps;
      lsp += fmaxf(x, 0.f) + log1pf(expf(-fabsf(x)));
      lrg += rg;
    }
  }
  if (lane == 0) { wsp[wv] = lsp; wrg[wv] = lrg; }
  __syncthreads();
  if (threadIdx.x == 0) {
    atomicAdd(&accums[0], wsp[0] + wsp[1] + wsp[2] + wsp[3]);
    atomicAdd(&accums[1], wrg[0] + wrg[1] + wrg[2] + wrg[3]);
  }
}

__global__ void finalize_kernel(const float* __restrict__ accums, float* __restrict__ out0) {
  if (threadIdx.x == 0 && blockIdx.x == 0) {
    float bpr = accums[0] / (float)BATCH;
    float reg = (accums[1] / (float)BATCH) * 1e-4f;
    float align = accums[2] / (float)((size_t)NI * D);
    out0[0] = bpr + reg + 0.1f * align;
  }
}

// ---------------- launch ----------------
extern "C" void kernel_launch(void* const* d_in, const int* in_sizes, int n_in,
                              void* d_out, int out_size, void* d_ws, size_t ws_size,
                              hipStream_t stream) {
  const int* edge_index = (const int*)d_in[0];
  const float* ew = (const float*)d_in[1];
  const int* bu = (const int*)d_in[2];
  const int* bp = (const int*)d_in[3];
  const int* bn = (const int*)d_in[4];
  const float* content = (const float*)d_in[5];
  const float* uemb = (const float*)d_in[6];
  const float* iemb = (const float*)d_in[7];
  const float* W = (const float*)d_in[8];
  const int* src = edge_index;
  const int* dst = edge_index + NE;
  float* outf = (float*)d_out;
  float* OUT = outf + 1;  // [NN][D] fp32 (4B-aligned only!)

  char* ws = (char*)d_ws;
  size_t off = 0;
  auto alloc = [&](size_t bytes) {
    void* p = ws + off;
    off = alignup(off + bytes, 256);
    return p;
  };
  unsigned int* x0b = (unsigned int*)alloc((size_t)NN * 64 * 4);
  unsigned int* y1b = (unsigned int*)alloc((size_t)NN * 64 * 4);
  unsigned int* y2b = (unsigned int*)alloc((size_t)NN * 64 * 4);
  float* degw = (float*)alloc((size_t)NN * 4);
  int* cnt = (int*)alloc((size_t)NN * 4);
  int* row_ptr = (int*)alloc((size_t)(NN + 1) * 4);
  int* cursor = (int*)alloc((size_t)NN * 4);
  int NB = (NN + 255) / 256;
  int* bsum = (int*)alloc((size_t)NB * 4);
  int* csrc = (int*)alloc((size_t)NE * 4);
  float* cnorm = (float*)alloc((size_t)NE * 4);
  unsigned short* Wb = (unsigned short*)alloc((size_t)D * CD * 2);
  float* accums = (float*)alloc(16);

  hipMemsetAsync(degw, 0, (size_t)NN * 4, stream);
  hipMemsetAsync(cnt, 0, (size_t)NN * 4, stream);
  hipMemsetAsync(accums, 0, 16, stream);

  deg_count_kernel<<<2048, 256, 0, stream>>>(dst, ew, degw, cnt);
  dinv_kernel<<<(NN + 255) / 256, 256, 0, stream>>>(degw);
  scan_p1<<<NB, 256, 0, stream>>>(cnt, bsum);
  scan_p2<<<1, 1024, 0, stream>>>(bsum, NB);
  scan_p3<<<NB, 256, 0, stream>>>(cnt, bsum, row_ptr);
  hipMemcpyAsync(cursor, row_ptr, (size_t)NN * 4, hipMemcpyDeviceToDevice, stream);
  csr_fill<<<2048, 256, 0, stream>>>(src, dst, ew, degw, cursor, csrc, cnorm);
  xconv_kernel<<<(NN * D / 8 + 255) / 256, 256, 0, stream>>>(uemb, iemb, x0b);
  wconv_kernel<<<(D * CD + 255) / 256, 256, 0, stream>>>(W, Wb);

  int LB = (NN + 3) / 4;
  gather_kernel<<<LB, 256, 0, stream>>>(row_ptr, csrc, cnorm, x0b, y1b);
  gather_kernel<<<LB, 256, 0, stream>>>(row_ptr, csrc, cnorm, y1b, y2b);
  final_kernel<<<LB, 256, 0, stream>>>(row_ptr, csrc, cnorm, x0b, y1b, y2b, OUT);

  align_mfma_kernel<<<(NI + 63) / 64, 256, 0, stream>>>(content, Wb, OUT + (size_t)NU * D, accums);
  loss_batch<<<64, 256, 0, stream>>>(bu, bp, bn, OUT, accums);
  finalize_kernel<<<1, 64, 0, stream>>>(accums, outf);
}

// Round 5
// 471.515 us; speedup vs baseline: 1.9694x; 1.1460x over previous
//
#include <hip/hip_runtime.h>
#include <math.h>

#define NU 100000
#define NI 50000
#define NN 150000
#define D 128
#define NE 1000000
#define CD 768
#define BATCH 4096

typedef short bf16x8 __attribute__((ext_vector_type(8)));
typedef float f32x4 __attribute__((ext_vector_type(4)));

static inline size_t alignup(size_t x, size_t a) { return (x + a - 1) / a * a; }

__device__ inline unsigned short f2bf(float f) {
  unsigned int u = __builtin_bit_cast(unsigned int, f);
  unsigned int r = (u + 0x7fffu + ((u >> 16) & 1u)) >> 16;
  return (unsigned short)r;
}
__device__ inline unsigned int pack2bf(float lo, float hi) {
  return (unsigned int)f2bf(lo) | ((unsigned int)f2bf(hi) << 16);
}
__device__ inline float bflo(unsigned int p) {
  return __builtin_bit_cast(float, p << 16);
}
__device__ inline float bfhi(unsigned int p) {
  return __builtin_bit_cast(float, p & 0xffff0000u);
}

// ---------------- fused prep: count+pos (even blocks) | xconv+wconv (odd blocks) ----------------
__global__ __launch_bounds__(256) void prep_kernel(
    const int* __restrict__ dst, int* __restrict__ cnt, int* __restrict__ cpos,
    const float* __restrict__ uemb, const float* __restrict__ iemb,
    unsigned int* __restrict__ x0b,
    const float* __restrict__ W, unsigned short* __restrict__ Wb) {
  int half = blockIdx.x >> 1;
  if ((blockIdx.x & 1) == 0) {
    // ---- edge counting with position capture (the only atomics in the pipeline)
    int i = half * 256 + threadIdx.x;
    for (; i < NE; i += 2048 * 256)
      cpos[i] = atomicAdd(&cnt[dst[i]], 1);
  } else {
    // ---- bf16 conversions, streaming (units of 8 floats)
    const size_t XT = (size_t)NN * D / 8;
    const size_t WT = (size_t)D * CD / 8;
    size_t t = (size_t)half * 256 + threadIdx.x;
    for (; t < XT + WT; t += (size_t)2048 * 256) {
      if (t < XT) {
        size_t f = t * 8;
        const float* p = (f < (size_t)NU * D) ? (uemb + f) : (iemb + (f - (size_t)NU * D));
        float4 a = *(const float4*)p;
        float4 b = *(const float4*)(p + 4);
        uint4 o;
        o.x = pack2bf(a.x, a.y); o.y = pack2bf(a.z, a.w);
        o.z = pack2bf(b.x, b.y); o.w = pack2bf(b.z, b.w);
        *(uint4*)(x0b + t * 4) = o;
      } else {
        size_t f = (t - XT) * 8;
        float4 a = *(const float4*)(W + f);
        float4 b = *(const float4*)(W + f + 4);
        uint4 o;
        o.x = (unsigned int)f2bf(a.x) | ((unsigned int)f2bf(a.y) << 16);
        o.y = (unsigned int)f2bf(a.z) | ((unsigned int)f2bf(a.w) << 16);
        o.z = (unsigned int)f2bf(b.x) | ((unsigned int)f2bf(b.y) << 16);
        o.w = (unsigned int)f2bf(b.z) | ((unsigned int)f2bf(b.w) << 16);
        *(uint4*)(Wb + f) = o;
      }
    }
  }
}

// ---------------- prefix scan for CSR row_ptr ----------------

__global__ void scan_p1(const int* __restrict__ cnt, int* __restrict__ bsum) {
  __shared__ int s[256];
  int b = blockIdx.x;
  int i = b * 256 + threadIdx.x;
  s[threadIdx.x] = (i < NN) ? cnt[i] : 0;
  __syncthreads();
  for (int off = 128; off; off >>= 1) {
    if (threadIdx.x < off) s[threadIdx.x] += s[threadIdx.x + off];
    __syncthreads();
  }
  if (threadIdx.x == 0) bsum[b] = s[0];
}

__global__ __launch_bounds__(1024) void scan_p2(int* __restrict__ bsum, int nb) {
  __shared__ int s[1024];
  int t = threadIdx.x;
  int v = (t < nb) ? bsum[t] : 0;
  s[t] = v;
  __syncthreads();
  for (int off = 1; off < 1024; off <<= 1) {
    int u = (t >= off) ? s[t - off] : 0;
    __syncthreads();
    s[t] += u;
    __syncthreads();
  }
  if (t < nb) bsum[t] = s[t] - v;
}

__global__ void scan_p3(const int* __restrict__ cnt, const int* __restrict__ bsum,
                        int* __restrict__ row_ptr) {
  __shared__ int s[256];
  int b = blockIdx.x;
  int i = b * 256 + threadIdx.x;
  s[threadIdx.x] = (i < NN) ? cnt[i] : 0;
  __syncthreads();
  for (int off = 1; off < 256; off <<= 1) {
    int t = (threadIdx.x >= off) ? s[threadIdx.x - off] : 0;
    __syncthreads();
    s[threadIdx.x] += t;
    __syncthreads();
  }
  if (i < NN) row_ptr[i + 1] = bsum[b] + s[threadIdx.x];
  if (i == 0) row_ptr[0] = 0;
}

// ---------------- CSR fill (no atomics) ----------------
__global__ void fill_kernel(const int* __restrict__ src, const int* __restrict__ dst,
                            const float* __restrict__ ew, const int* __restrict__ row_ptr,
                            const int* __restrict__ cpos, int* __restrict__ csrc,
                            float* __restrict__ cew) {
  int i = blockIdx.x * blockDim.x + threadIdx.x;
  int stride = gridDim.x * blockDim.x;
  for (; i < NE; i += stride) {
    int p = row_ptr[dst[i]] + cpos[i];
    csrc[p] = src[i];
    cew[p] = ew[i];
  }
}

// ---------------- degree from CSR row sums + rsqrt ----------------
__global__ void degrow_kernel(const int* __restrict__ row_ptr, const float* __restrict__ cew,
                              float* __restrict__ dinv) {
  int n = blockIdx.x * blockDim.x + threadIdx.x;
  if (n >= NN) return;
  int beg = row_ptr[n], end = row_ptr[n + 1];
  float s = 0.f;
  for (int p = beg; p < end; ++p) s += cew[p];
  dinv[n] = (s > 0.f) ? rsqrtf(s) : 0.f;
}

// ---------------- per-slot partial norm: cnorm = dinv[src] * ew ----------------
__global__ void norm_kernel(const int* __restrict__ csrc, const float* __restrict__ cew,
                            const float* __restrict__ dinv, float* __restrict__ cnorm) {
  int i = blockIdx.x * blockDim.x + threadIdx.x;
  int stride = gridDim.x * blockDim.x;
  for (; i < NE; i += stride) cnorm[i] = dinv[csrc[i]] * cew[i];
}

// ---------------- propagation layers (bf16 state; dinv[dst] factored out) ----------------
__global__ __launch_bounds__(256) void gather_kernel(
    const int* __restrict__ row_ptr, const int* __restrict__ csrc,
    const float* __restrict__ cnorm, const float* __restrict__ dinv,
    const unsigned int* __restrict__ xin, unsigned int* __restrict__ yout) {
  int wv = threadIdx.x >> 6, lane = threadIdx.x & 63;
  int n = blockIdx.x * 4 + wv;
  if (n >= NN) return;
  int beg = row_ptr[n], end = row_ptr[n + 1];
  float a0 = 0.f, a1 = 0.f;
  int j = beg;
  for (; j + 2 <= end; j += 2) {
    int s0 = csrc[j], s1 = csrc[j + 1];
    float w0 = cnorm[j], w1 = cnorm[j + 1];
    unsigned int p0 = xin[(size_t)s0 * 64 + lane];
    unsigned int p1 = xin[(size_t)s1 * 64 + lane];
    a0 = fmaf(w0, bflo(p0), a0); a1 = fmaf(w0, bfhi(p0), a1);
    a0 = fmaf(w1, bflo(p1), a0); a1 = fmaf(w1, bfhi(p1), a1);
  }
  if (j < end) {
    int s0 = csrc[j];
    float w0 = cnorm[j];
    unsigned int p0 = xin[(size_t)s0 * 64 + lane];
    a0 = fmaf(w0, bflo(p0), a0); a1 = fmaf(w0, bfhi(p0), a1);
  }
  float sc = dinv[n];
  yout[(size_t)n * 64 + lane] = pack2bf(a0 * sc, a1 * sc);
}

// final layer: gather y3 from y2b, then OUT = 0.25*(x0+y1+y2+y3) in fp32
__global__ __launch_bounds__(256) void final_kernel(
    const int* __restrict__ row_ptr, const int* __restrict__ csrc,
    const float* __restrict__ cnorm, const float* __restrict__ dinv,
    const unsigned int* __restrict__ x0b, const unsigned int* __restrict__ y1b,
    const unsigned int* __restrict__ y2b, float* __restrict__ OUT) {
  int wv = threadIdx.x >> 6, lane = threadIdx.x & 63;
  int n = blockIdx.x * 4 + wv;
  if (n >= NN) return;
  int beg = row_ptr[n], end = row_ptr[n + 1];
  float a0 = 0.f, a1 = 0.f;
  int j = beg;
  for (; j + 2 <= end; j += 2) {
    int s0 = csrc[j], s1 = csrc[j + 1];
    float w0 = cnorm[j], w1 = cnorm[j + 1];
    unsigned int p0 = y2b[(size_t)s0 * 64 + lane];
    unsigned int p1 = y2b[(size_t)s1 * 64 + lane];
    a0 = fmaf(w0, bflo(p0), a0); a1 = fmaf(w0, bfhi(p0), a1);
    a0 = fmaf(w1, bflo(p1), a0); a1 = fmaf(w1, bfhi(p1), a1);
  }
  if (j < end) {
    int s0 = csrc[j];
    float w0 = cnorm[j];
    unsigned int p0 = y2b[(size_t)s0 * 64 + lane];
    a0 = fmaf(w0, bflo(p0), a0); a1 = fmaf(w0, bfhi(p0), a1);
  }
  float sc = dinv[n];
  size_t r = (size_t)n * 64 + lane;
  unsigned int q0 = x0b[r], q1 = y1b[r], q2 = y2b[r];
  float s0f = bflo(q0) + bflo(q1) + bflo(q2) + a0 * sc;
  float s1f = bfhi(q0) + bfhi(q1) + bfhi(q2) + a1 * sc;
  size_t o = (size_t)n * D + lane * 2;
  OUT[o] = s0f * 0.25f;
  OUT[o + 1] = s1f * 0.25f;
}

// ---------------- content projection + align MSE (bf16 MFMA, fused) ----------------
__global__ __launch_bounds__(256) void align_mfma_kernel(
    const float* __restrict__ content, const unsigned short* __restrict__ Wb,
    const float* __restrict__ ifinal, float* __restrict__ accums) {
  __shared__ unsigned short Asm[64 * 64];
  __shared__ unsigned short Bsm[128 * 64];
  __shared__ float wred[4];

  int tid = threadIdx.x;
  int w = tid >> 6, lane = tid & 63;
  int i0 = blockIdx.x * 64;
  int lrow = lane & 15, kq = lane >> 4;

  f32x4 acc[4][2];
#pragma unroll
  for (int rt = 0; rt < 4; ++rt)
#pragma unroll
    for (int ct = 0; ct < 2; ++ct) acc[rt][ct] = (f32x4){0.f, 0.f, 0.f, 0.f};

  int ar = tid & 63, akc = tid >> 6;
  int br = tid & 127, bh = tid >> 7;
  int arow_g = (i0 + ar < NI) ? (i0 + ar) : (NI - 1);
  const float* aG = content + (size_t)arow_g * CD + akc * 16;
  const unsigned short* bG = Wb + (size_t)br * CD + bh * 32;
  char* aL = (char*)Asm + ar * 128;
  int aswz = (ar & 7) << 4;
  char* bL = (char*)Bsm + br * 128;
  int bswz = (br & 7) << 4;

  for (int k0 = 0; k0 < CD; k0 += 64) {
    unsigned short tmp[16];
#pragma unroll
    for (int q4 = 0; q4 < 4; ++q4) {
      float4 v = *(const float4*)(aG + k0 + q4 * 4);
      tmp[q4 * 4 + 0] = f2bf(v.x); tmp[q4 * 4 + 1] = f2bf(v.y);
      tmp[q4 * 4 + 2] = f2bf(v.z); tmp[q4 * 4 + 3] = f2bf(v.w);
    }
    *(uint4*)(aL + ((akc * 32) ^ aswz)) = *(uint4*)(tmp);
    *(uint4*)(aL + ((akc * 32 + 16) ^ aswz)) = *(uint4*)(tmp + 8);
#pragma unroll
    for (int q = 0; q < 4; ++q) {
      uint4 v = *(const uint4*)(bG + k0 + q * 8);
      *(uint4*)(bL + ((bh * 64 + q * 16) ^ bswz)) = v;
    }
    __syncthreads();
#pragma unroll
    for (int ks = 0; ks < 2; ++ks) {
      int kbyte = ks * 64 + kq * 16;
      bf16x8 af[4], bfr[2];
#pragma unroll
      for (int rt = 0; rt < 4; ++rt) {
        int row = rt * 16 + lrow;
        af[rt] = *(const bf16x8*)((char*)Asm + row * 128 + (kbyte ^ ((row & 7) << 4)));
      }
#pragma unroll
      for (int ct = 0; ct < 2; ++ct) {
        int row = w * 32 + ct * 16 + lrow;
        bfr[ct] = *(const bf16x8*)((char*)Bsm + row * 128 + (kbyte ^ ((row & 7) << 4)));
      }
#pragma unroll
      for (int rt = 0; rt < 4; ++rt)
#pragma unroll
        for (int ct = 0; ct < 2; ++ct)
          acc[rt][ct] = __builtin_amdgcn_mfma_f32_16x16x32_bf16(af[rt], bfr[ct], acc[rt][ct], 0, 0, 0);
    }
    __syncthreads();
  }

  float s = 0.f;
#pragma unroll
  for (int rt = 0; rt < 4; ++rt) {
#pragma unroll
    for (int j = 0; j < 4; ++j) {
      int it = i0 + rt * 16 + kq * 4 + j;
      if (it < NI) {
        int dcol0 = w * 32 + lrow;
        float r0 = ifinal[(size_t)it * D + dcol0];
        float r1 = ifinal[(size_t)it * D + dcol0 + 16];
        float d0 = r0 - acc[rt][0][j];
        float d1 = r1 - acc[rt][1][j];
        s = fmaf(d0, d0, s);
        s = fmaf(d1, d1, s);
      }
    }
  }
  for (int off = 32; off; off >>= 1) s += __shfl_down(s, off);
  if (lane == 0) wred[w] = s;
  __syncthreads();
  if (tid == 0) atomicAdd(&accums[2], wred[0] + wred[1] + wred[2] + wred[3]);
}

// ---------------- BPR + reg loss over batch (block-reduced atomics) ----------------
__global__ __launch_bounds__(256) void loss_batch(
    const int* __restrict__ bu, const int* __restrict__ bp, const int* __restrict__ bn,
    const float* __restrict__ OUT, float* __restrict__ accums) {
  __shared__ float wsp[4], wrg[4];
  int wv = threadIdx.x >> 6, lane = threadIdx.x & 63;
  int gw = blockIdx.x * 4 + wv;
  int nw = gridDim.x * 4;
  float lsp = 0.f, lrg = 0.f;
  for (int b = gw; b < BATCH; b += nw) {
    const float* u = OUT + (size_t)bu[b] * D;
    const float* ip = OUT + ((size_t)NU + bp[b]) * D;
    const float* in_ = OUT + ((size_t)NU + bn[b]) * D;
    float u0 = u[lane], u1 = u[lane + 64];
    float p0 = ip[lane], p1 = ip[lane + 64];
    float n0 = in_[lane], n1 = in_[lane + 64];
    float ps = u0 * p0 + u1 * p1;
    float ns = u0 * n0 + u1 * n1;
    float rg = u0 * u0 + u1 * u1 + p0 * p0 + p1 * p1 + n0 * n0 + n1 * n1;
    for (int off = 32; off; off >>= 1) {
      ps += __shfl_down(ps, off);
      ns += __shfl_down(ns, off);
      rg += __shfl_down(rg, off);
    }
    if (lane == 0) {
      float x = ns - ps;
      lsp += fmaxf(x, 0.f) + log1pf(expf(-fabsf(x)));
      lrg += rg;
    }
  }
  if (lane == 0) { wsp[wv] = lsp; wrg[wv] = lrg; }
  __syncthreads();
  if (threadIdx.x == 0) {
    atomicAdd(&accums[0], wsp[0] + wsp[1] + wsp[2] + wsp[3]);
    atomicAdd(&accums[1], wrg[0] + wrg[1] + wrg[2] + wrg[3]);
  }
}

__global__ void finalize_kernel(const float* __restrict__ accums, float* __restrict__ out0) {
  if (threadIdx.x == 0 && blockIdx.x == 0) {
    float bpr = accums[0] / (float)BATCH;
    float reg = (accums[1] / (float)BATCH) * 1e-4f;
    float align = accums[2] / (float)((size_t)NI * D);
    out0[0] = bpr + reg + 0.1f * align;
  }
}

// ---------------- launch ----------------
extern "C" void kernel_launch(void* const* d_in, const int* in_sizes, int n_in,
                              void* d_out, int out_size, void* d_ws, size_t ws_size,
                              hipStream_t stream) {
  const int* edge_index = (const int*)d_in[0];
  const float* ew = (const float*)d_in[1];
  const int* bu = (const int*)d_in[2];
  const int* bp = (const int*)d_in[3];
  const int* bn = (const int*)d_in[4];
  const float* content = (const float*)d_in[5];
  const float* uemb = (const float*)d_in[6];
  const float* iemb = (const float*)d_in[7];
  const float* W = (const float*)d_in[8];
  const int* src = edge_index;
  const int* dst = edge_index + NE;
  float* outf = (float*)d_out;
  float* OUT = outf + 1;  // [NN][D] fp32 (4B-aligned only!)

  char* ws = (char*)d_ws;
  size_t off = 0;
  auto alloc = [&](size_t bytes) {
    void* p = ws + off;
    off = alignup(off + bytes, 256);
    return p;
  };
  unsigned int* x0b = (unsigned int*)alloc((size_t)NN * 64 * 4);
  unsigned int* y1b = (unsigned int*)alloc((size_t)NN * 64 * 4);
  unsigned int* y2b = (unsigned int*)alloc((size_t)NN * 64 * 4);
  float* dinv = (float*)alloc((size_t)NN * 4);
  int* cnt = (int*)alloc((size_t)NN * 4);
  int* row_ptr = (int*)alloc((size_t)(NN + 1) * 4);
  int NB = (NN + 255) / 256;
  int* bsum = (int*)alloc((size_t)NB * 4);
  int* cpos = (int*)alloc((size_t)NE * 4);
  int* csrc = (int*)alloc((size_t)NE * 4);
  float* cew = (float*)alloc((size_t)NE * 4);
  float* cnorm = (float*)alloc((size_t)NE * 4);
  unsigned short* Wb = (unsigned short*)alloc((size_t)D * CD * 2);
  float* accums = (float*)alloc(16);

  hipMemsetAsync(cnt, 0, (size_t)NN * 4, stream);
  hipMemsetAsync(accums, 0, 16, stream);

  prep_kernel<<<4096, 256, 0, stream>>>(dst, cnt, cpos, uemb, iemb, x0b, W, Wb);
  scan_p1<<<NB, 256, 0, stream>>>(cnt, bsum);
  scan_p2<<<1, 1024, 0, stream>>>(bsum, NB);
  scan_p3<<<NB, 256, 0, stream>>>(cnt, bsum, row_ptr);
  fill_kernel<<<2048, 256, 0, stream>>>(src, dst, ew, row_ptr, cpos, csrc, cew);
  degrow_kernel<<<NB, 256, 0, stream>>>(row_ptr, cew, dinv);
  norm_kernel<<<2048, 256, 0, stream>>>(csrc, cew, dinv, cnorm);

  int LB = (NN + 3) / 4;
  gather_kernel<<<LB, 256, 0, stream>>>(row_ptr, csrc, cnorm, dinv, x0b, y1b);
  gather_kernel<<<LB, 256, 0, stream>>>(row_ptr, csrc, cnorm, dinv, y1b, y2b);
  final_kernel<<<LB, 256, 0, stream>>>(row_ptr, csrc, cnorm, dinv, x0b, y1b, y2b, OUT);

  align_mfma_kernel<<<(NI + 63) / 64, 256, 0, stream>>>(content, Wb, OUT + (size_t)NU * D, accums);
  loss_batch<<<64, 256, 0, stream>>>(bu, bp, bn, OUT, accums);
  finalize_kernel<<<1, 64, 0, stream>>>(accums, outf);
}

// Round 6
// 431.047 us; speedup vs baseline: 2.1543x; 1.0939x over previous
//
#include <hip/hip_runtime.h>
#include <math.h>

#define NU 100000
#define NI 50000
#define NN 150000
#define D 128
#define NE 1000000
#define CD 768
#define BATCH 4096

typedef short bf16x8 __attribute__((ext_vector_type(8)));
typedef float f32x4 __attribute__((ext_vector_type(4)));

static inline size_t alignup(size_t x, size_t a) { return (x + a - 1) / a * a; }

__device__ inline unsigned short f2bf(float f) {
  unsigned int u = __builtin_bit_cast(unsigned int, f);
  unsigned int r = (u + 0x7fffu + ((u >> 16) & 1u)) >> 16;
  return (unsigned short)r;
}
__device__ inline unsigned int pack2bf(float lo, float hi) {
  return (unsigned int)f2bf(lo) | ((unsigned int)f2bf(hi) << 16);
}
__device__ inline float bflo(unsigned int p) {
  return __builtin_bit_cast(float, p << 16);
}
__device__ inline float bfhi(unsigned int p) {
  return __builtin_bit_cast(float, p & 0xffff0000u);
}

// ---------------- fused prep: count+pos (even blocks) | xconv+wconv (odd blocks) ----------------
__global__ __launch_bounds__(256) void prep_kernel(
    const int* __restrict__ dst, int* __restrict__ cnt, int* __restrict__ cpos,
    const float* __restrict__ uemb, const float* __restrict__ iemb,
    unsigned int* __restrict__ x0b,
    const float* __restrict__ W, unsigned short* __restrict__ Wb) {
  int half = blockIdx.x >> 1;
  if ((blockIdx.x & 1) == 0) {
    int i = half * 256 + threadIdx.x;
    for (; i < NE; i += 2048 * 256)
      cpos[i] = atomicAdd(&cnt[dst[i]], 1);
  } else {
    const size_t XT = (size_t)NN * D / 8;
    const size_t WT = (size_t)D * CD / 8;
    size_t t = (size_t)half * 256 + threadIdx.x;
    for (; t < XT + WT; t += (size_t)2048 * 256) {
      if (t < XT) {
        size_t f = t * 8;
        const float* p = (f < (size_t)NU * D) ? (uemb + f) : (iemb + (f - (size_t)NU * D));
        float4 a = *(const float4*)p;
        float4 b = *(const float4*)(p + 4);
        uint4 o;
        o.x = pack2bf(a.x, a.y); o.y = pack2bf(a.z, a.w);
        o.z = pack2bf(b.x, b.y); o.w = pack2bf(b.z, b.w);
        *(uint4*)(x0b + t * 4) = o;
      } else {
        size_t f = (t - XT) * 8;
        float4 a = *(const float4*)(W + f);
        float4 b = *(const float4*)(W + f + 4);
        uint4 o;
        o.x = (unsigned int)f2bf(a.x) | ((unsigned int)f2bf(a.y) << 16);
        o.y = (unsigned int)f2bf(a.z) | ((unsigned int)f2bf(a.w) << 16);
        o.z = (unsigned int)f2bf(b.x) | ((unsigned int)f2bf(b.y) << 16);
        o.w = (unsigned int)f2bf(b.z) | ((unsigned int)f2bf(b.w) << 16);
        *(uint4*)(Wb + f) = o;
      }
    }
  }
}

// ---------------- prefix scan for CSR row_ptr ----------------

__global__ void scan_p1(const int* __restrict__ cnt, int* __restrict__ bsum) {
  __shared__ int s[256];
  int b = blockIdx.x;
  int i = b * 256 + threadIdx.x;
  s[threadIdx.x] = (i < NN) ? cnt[i] : 0;
  __syncthreads();
  for (int off = 128; off; off >>= 1) {
    if (threadIdx.x < off) s[threadIdx.x] += s[threadIdx.x + off];
    __syncthreads();
  }
  if (threadIdx.x == 0) bsum[b] = s[0];
}

__global__ __launch_bounds__(1024) void scan_p2(int* __restrict__ bsum, int nb) {
  __shared__ int s[1024];
  int t = threadIdx.x;
  int v = (t < nb) ? bsum[t] : 0;
  s[t] = v;
  __syncthreads();
  for (int off = 1; off < 1024; off <<= 1) {
    int u = (t >= off) ? s[t - off] : 0;
    __syncthreads();
    s[t] += u;
    __syncthreads();
  }
  if (t < nb) bsum[t] = s[t] - v;
}

__global__ void scan_p3(const int* __restrict__ cnt, const int* __restrict__ bsum,
                        int* __restrict__ row_ptr) {
  __shared__ int s[256];
  int b = blockIdx.x;
  int i = b * 256 + threadIdx.x;
  s[threadIdx.x] = (i < NN) ? cnt[i] : 0;
  __syncthreads();
  for (int off = 1; off < 256; off <<= 1) {
    int t = (threadIdx.x >= off) ? s[threadIdx.x - off] : 0;
    __syncthreads();
    s[threadIdx.x] += t;
    __syncthreads();
  }
  if (i < NN) row_ptr[i + 1] = bsum[b] + s[threadIdx.x];
  if (i == 0) row_ptr[0] = 0;
}

// ---------------- CSR fill (no atomics) ----------------
__global__ void fill_kernel(const int* __restrict__ src, const int* __restrict__ dst,
                            const float* __restrict__ ew, const int* __restrict__ row_ptr,
                            const int* __restrict__ cpos, int* __restrict__ csrc,
                            float* __restrict__ cew) {
  int i = blockIdx.x * blockDim.x + threadIdx.x;
  int stride = gridDim.x * blockDim.x;
  for (; i < NE; i += stride) {
    int p = row_ptr[dst[i]] + cpos[i];
    csrc[p] = src[i];
    cew[p] = ew[i];
  }
}

// ---------------- degree from CSR row sums + rsqrt ----------------
__global__ void degrow_kernel(const int* __restrict__ row_ptr, const float* __restrict__ cew,
                              float* __restrict__ dinv) {
  int n = blockIdx.x * blockDim.x + threadIdx.x;
  if (n >= NN) return;
  int beg = row_ptr[n], end = row_ptr[n + 1];
  float s = 0.f;
  for (int p = beg; p < end; ++p) s += cew[p];
  dinv[n] = (s > 0.f) ? rsqrtf(s) : 0.f;
}

// ---------------- per-slot partial norm: cnorm = dinv[src] * ew ----------------
__global__ void norm_kernel(const int* __restrict__ csrc, const float* __restrict__ cew,
                            const float* __restrict__ dinv, float* __restrict__ cnorm) {
  int i = blockIdx.x * blockDim.x + threadIdx.x;
  int stride = gridDim.x * blockDim.x;
  for (; i < NE; i += stride) cnorm[i] = dinv[csrc[i]] * cew[i];
}

// ---------------- propagation layers (bf16 state; dinv[dst] factored out) ----------------
__global__ __launch_bounds__(256) void gather_kernel(
    const int* __restrict__ row_ptr, const int* __restrict__ csrc,
    const float* __restrict__ cnorm, const float* __restrict__ dinv,
    const unsigned int* __restrict__ xin, unsigned int* __restrict__ yout) {
  int wv = threadIdx.x >> 6, lane = threadIdx.x & 63;
  int n = blockIdx.x * 4 + wv;
  if (n >= NN) return;
  int beg = row_ptr[n], end = row_ptr[n + 1];
  float a0 = 0.f, a1 = 0.f;
  int j = beg;
  for (; j + 2 <= end; j += 2) {
    int s0 = csrc[j], s1 = csrc[j + 1];
    float w0 = cnorm[j], w1 = cnorm[j + 1];
    unsigned int p0 = xin[(size_t)s0 * 64 + lane];
    unsigned int p1 = xin[(size_t)s1 * 64 + lane];
    a0 = fmaf(w0, bflo(p0), a0); a1 = fmaf(w0, bfhi(p0), a1);
    a0 = fmaf(w1, bflo(p1), a0); a1 = fmaf(w1, bfhi(p1), a1);
  }
  if (j < end) {
    int s0 = csrc[j];
    float w0 = cnorm[j];
    unsigned int p0 = xin[(size_t)s0 * 64 + lane];
    a0 = fmaf(w0, bflo(p0), a0); a1 = fmaf(w0, bfhi(p0), a1);
  }
  float sc = dinv[n];
  yout[(size_t)n * 64 + lane] = pack2bf(a0 * sc, a1 * sc);
}

// final layer: gather y3 from y2b, then OUT = 0.25*(x0+y1+y2+y3) in fp32
__global__ __launch_bounds__(256) void final_kernel(
    const int* __restrict__ row_ptr, const int* __restrict__ csrc,
    const float* __restrict__ cnorm, const float* __restrict__ dinv,
    const unsigned int* __restrict__ x0b, const unsigned int* __restrict__ y1b,
    const unsigned int* __restrict__ y2b, float* __restrict__ OUT) {
  int wv = threadIdx.x >> 6, lane = threadIdx.x & 63;
  int n = blockIdx.x * 4 + wv;
  if (n >= NN) return;
  int beg = row_ptr[n], end = row_ptr[n + 1];
  float a0 = 0.f, a1 = 0.f;
  int j = beg;
  for (; j + 2 <= end; j += 2) {
    int s0 = csrc[j], s1 = csrc[j + 1];
    float w0 = cnorm[j], w1 = cnorm[j + 1];
    unsigned int p0 = y2b[(size_t)s0 * 64 + lane];
    unsigned int p1 = y2b[(size_t)s1 * 64 + lane];
    a0 = fmaf(w0, bflo(p0), a0); a1 = fmaf(w0, bfhi(p0), a1);
    a0 = fmaf(w1, bflo(p1), a0); a1 = fmaf(w1, bfhi(p1), a1);
  }
  if (j < end) {
    int s0 = csrc[j];
    float w0 = cnorm[j];
    unsigned int p0 = y2b[(size_t)s0 * 64 + lane];
    a0 = fmaf(w0, bflo(p0), a0); a1 = fmaf(w0, bfhi(p0), a1);
  }
  float sc = dinv[n];
  size_t r = (size_t)n * 64 + lane;
  unsigned int q0 = x0b[r], q1 = y1b[r], q2 = y2b[r];
  float s0f = bflo(q0) + bflo(q1) + bflo(q2) + a0 * sc;
  float s1f = bfhi(q0) + bfhi(q1) + bfhi(q2) + a1 * sc;
  size_t o = (size_t)n * D + lane * 2;
  OUT[o] = s0f * 0.25f;
  OUT[o + 1] = s1f * 0.25f;
}

// ---------------- content projection + align MSE (bf16 MFMA, double-buffered, 8 waves) ---------
// Block: 512 threads = 8 waves; tile = 64 items x 128 D; BK=64; wave w owns D-cols [16w,16w+16).
__global__ __launch_bounds__(512) void align_mfma_kernel(
    const float* __restrict__ content, const unsigned short* __restrict__ Wb,
    const float* __restrict__ ifinal, float* __restrict__ accums) {
  __shared__ unsigned short Asm[2][64 * 64];   // 2 x 8 KB, XOR-swizzled rows
  __shared__ unsigned short Bsm[2][128 * 64];  // 2 x 16 KB
  __shared__ float wred[8];

  int tid = threadIdx.x;
  int w = tid >> 6, lane = tid & 63;
  int i0 = blockIdx.x * 64;
  int lrow = lane & 15, kq = lane >> 4;

  f32x4 acc[4];
#pragma unroll
  for (int rt = 0; rt < 4; ++rt) acc[rt] = (f32x4){0.f, 0.f, 0.f, 0.f};

  // staging decomposition: t = r*8 + c8
  int sr = tid >> 3, c8 = tid & 7;
  int arow_g = (i0 + sr < NI) ? (i0 + sr) : (NI - 1);
  const float* aG = content + (size_t)arow_g * CD + c8 * 8;
  const unsigned short* bG0 = Wb + (size_t)sr * CD + c8 * 8;
  const unsigned short* bG1 = Wb + (size_t)(sr + 64) * CD + c8 * 8;
  int aoff = (c8 * 16) ^ ((sr & 7) << 4);           // byte offset in A row
  int boff0 = aoff;                                  // same row swizzle for B row sr
  int boff1 = (c8 * 16) ^ (((sr + 64) & 7) << 4);

  // ---- prologue: stage k0=0 into buffer 0 ----
  {
    float4 a = *(const float4*)(aG);
    float4 b = *(const float4*)(aG + 4);
    uint4 o;
    o.x = pack2bf(a.x, a.y); o.y = pack2bf(a.z, a.w);
    o.z = pack2bf(b.x, b.y); o.w = pack2bf(b.z, b.w);
    *(uint4*)((char*)Asm[0] + sr * 128 + aoff) = o;
    *(uint4*)((char*)Bsm[0] + sr * 128 + boff0) = *(const uint4*)(bG0);
    *(uint4*)((char*)Bsm[0] + (sr + 64) * 128 + boff1) = *(const uint4*)(bG1);
  }

  for (int kk = 0; kk < 6; ++kk) {
    __syncthreads();
    int cur = kk & 1, nxt = cur ^ 1;
    bool more = kk < 5;
    float4 na, nb;
    uint4 nb0, nb1;
    if (more) {
      int k0 = (kk + 1) * 64;
      na = *(const float4*)(aG + k0);
      nb = *(const float4*)(aG + k0 + 4);
      nb0 = *(const uint4*)(bG0 + k0);
      nb1 = *(const uint4*)(bG1 + k0);
    }
    // ---- MFMA on cur ----
#pragma unroll
    for (int ks = 0; ks < 2; ++ks) {
      int kbyte = ks * 64 + kq * 16;
      bf16x8 af[4], bfr;
#pragma unroll
      for (int rt = 0; rt < 4; ++rt) {
        int row = rt * 16 + lrow;
        af[rt] = *(const bf16x8*)((char*)Asm[cur] + row * 128 + (kbyte ^ ((row & 7) << 4)));
      }
      {
        int row = w * 16 + lrow;
        bfr = *(const bf16x8*)((char*)Bsm[cur] + row * 128 + (kbyte ^ ((row & 7) << 4)));
      }
#pragma unroll
      for (int rt = 0; rt < 4; ++rt)
        acc[rt] = __builtin_amdgcn_mfma_f32_16x16x32_bf16(af[rt], bfr, acc[rt], 0, 0, 0);
    }
    // ---- write next buffer ----
    if (more) {
      uint4 o;
      o.x = pack2bf(na.x, na.y); o.y = pack2bf(na.z, na.w);
      o.z = pack2bf(nb.x, nb.y); o.w = pack2bf(nb.z, nb.w);
      *(uint4*)((char*)Asm[nxt] + sr * 128 + aoff) = o;
      *(uint4*)((char*)Bsm[nxt] + sr * 128 + boff0) = nb0;
      *(uint4*)((char*)Bsm[nxt] + (sr + 64) * 128 + boff1) = nb1;
    }
  }

  // ---- fused MSE epilogue ----
  // C/D layout: col = lane&15 (-> D col = w*16+lrow), row = kq*4 + j (+16*rt)
  float s = 0.f;
  int dcol = w * 16 + lrow;
#pragma unroll
  for (int rt = 0; rt < 4; ++rt) {
#pragma unroll
    for (int j = 0; j < 4; ++j) {
      int it = i0 + rt * 16 + kq * 4 + j;
      if (it < NI) {
        float r0 = ifinal[(size_t)it * D + dcol];
        float d0 = r0 - acc[rt][j];
        s = fmaf(d0, d0, s);
      }
    }
  }
  for (int off = 32; off; off >>= 1) s += __shfl_down(s, off);
  if (lane == 0) wred[w] = s;
  __syncthreads();
  if (tid == 0) {
    float t = 0.f;
#pragma unroll
    for (int q = 0; q < 8; ++q) t += wred[q];
    atomicAdd(&accums[2], t);
  }
}

// ---------------- BPR + reg loss over batch (block-reduced atomics) ----------------
__global__ __launch_bounds__(256) void loss_batch(
    const int* __restrict__ bu, const int* __restrict__ bp, const int* __restrict__ bn,
    const float* __restrict__ OUT, float* __restrict__ accums) {
  __shared__ float wsp[4], wrg[4];
  int wv = threadIdx.x >> 6, lane = threadIdx.x & 63;
  int gw = blockIdx.x * 4 + wv;
  int nw = gridDim.x * 4;
  float lsp = 0.f, lrg = 0.f;
  for (int b = gw; b < BATCH; b += nw) {
    const float* u = OUT + (size_t)bu[b] * D;
    const float* ip = OUT + ((size_t)NU + bp[b]) * D;
    const float* in_ = OUT + ((size_t)NU + bn[b]) * D;
    float u0 = u[lane], u1 = u[lane + 64];
    float p0 = ip[lane], p1 = ip[lane + 64];
    float n0 = in_[lane], n1 = in_[lane + 64];
    float ps = u0 * p0 + u1 * p1;
    float ns = u0 * n0 + u1 * n1;
    float rg = u0 * u0 + u1 * u1 + p0 * p0 + p1 * p1 + n0 * n0 + n1 * n1;
    for (int off = 32; off; off >>= 1) {
      ps += __shfl_down(ps, off);
      ns += __shfl_down(ns, off);
      rg += __shfl_down(rg, off);
    }
    if (lane == 0) {
      float x = ns - ps;
      lsp += fmaxf(x, 0.f) + log1pf(expf(-fabsf(x)));
      lrg += rg;
    }
  }
  if (lane == 0) { wsp[wv] = lsp; wrg[wv] = lrg; }
  __syncthreads();
  if (threadIdx.x == 0) {
    atomicAdd(&accums[0], wsp[0] + wsp[1] + wsp[2] + wsp[3]);
    atomicAdd(&accums[1], wrg[0] + wrg[1] + wrg[2] + wrg[3]);
  }
}

__global__ void finalize_kernel(const float* __restrict__ accums, float* __restrict__ out0) {
  if (threadIdx.x == 0 && blockIdx.x == 0) {
    float bpr = accums[0] / (float)BATCH;
    float reg = (accums[1] / (float)BATCH) * 1e-4f;
    float align = accums[2] / (float)((size_t)NI * D);
    out0[0] = bpr + reg + 0.1f * align;
  }
}

// ---------------- launch ----------------
extern "C" void kernel_launch(void* const* d_in, const int* in_sizes, int n_in,
                              void* d_out, int out_size, void* d_ws, size_t ws_size,
                              hipStream_t stream) {
  const int* edge_index = (const int*)d_in[0];
  const float* ew = (const float*)d_in[1];
  const int* bu = (const int*)d_in[2];
  const int* bp = (const int*)d_in[3];
  const int* bn = (const int*)d_in[4];
  const float* content = (const float*)d_in[5];
  const float* uemb = (const float*)d_in[6];
  const float* iemb = (const float*)d_in[7];
  const float* W = (const float*)d_in[8];
  const int* src = edge_index;
  const int* dst = edge_index + NE;
  float* outf = (float*)d_out;
  float* OUT = outf + 1;  // [NN][D] fp32 (4B-aligned only!)

  char* ws = (char*)d_ws;
  size_t off = 0;
  auto alloc = [&](size_t bytes) {
    void* p = ws + off;
    off = alignup(off + bytes, 256);
    return p;
  };
  unsigned int* x0b = (unsigned int*)alloc((size_t)NN * 64 * 4);
  unsigned int* y1b = (unsigned int*)alloc((size_t)NN * 64 * 4);
  unsigned int* y2b = (unsigned int*)alloc((size_t)NN * 64 * 4);
  float* dinv = (float*)alloc((size_t)NN * 4);
  int* cnt = (int*)alloc((size_t)NN * 4);
  int* row_ptr = (int*)alloc((size_t)(NN + 1) * 4);
  int NB = (NN + 255) / 256;
  int* bsum = (int*)alloc((size_t)NB * 4);
  int* cpos = (int*)alloc((size_t)NE * 4);
  int* csrc = (int*)alloc((size_t)NE * 4);
  float* cew = (float*)alloc((size_t)NE * 4);
  float* cnorm = (float*)alloc((size_t)NE * 4);
  unsigned short* Wb = (unsigned short*)alloc((size_t)D * CD * 2);
  float* accums = (float*)alloc(16);

  hipMemsetAsync(cnt, 0, (size_t)NN * 4, stream);
  hipMemsetAsync(accums, 0, 16, stream);

  prep_kernel<<<4096, 256, 0, stream>>>(dst, cnt, cpos, uemb, iemb, x0b, W, Wb);
  scan_p1<<<NB, 256, 0, stream>>>(cnt, bsum);
  scan_p2<<<1, 1024, 0, stream>>>(bsum, NB);
  scan_p3<<<NB, 256, 0, stream>>>(cnt, bsum, row_ptr);
  fill_kernel<<<2048, 256, 0, stream>>>(src, dst, ew, row_ptr, cpos, csrc, cew);
  degrow_kernel<<<NB, 256, 0, stream>>>(row_ptr, cew, dinv);
  norm_kernel<<<2048, 256, 0, stream>>>(csrc, cew, dinv, cnorm);

  int LB = (NN + 3) / 4;
  gather_kernel<<<LB, 256, 0, stream>>>(row_ptr, csrc, cnorm, dinv, x0b, y1b);
  gather_kernel<<<LB, 256, 0, stream>>>(row_ptr, csrc, cnorm, dinv, y1b, y2b);
  final_kernel<<<LB, 256, 0, stream>>>(row_ptr, csrc, cnorm, dinv, x0b, y1b, y2b, OUT);

  align_mfma_kernel<<<(NI + 63) / 64, 512, 0, stream>>>(content, Wb, OUT + (size_t)NU * D, accums);
  loss_batch<<<64, 256, 0, stream>>>(bu, bp, bn, OUT, accums);
  finalize_kernel<<<1, 64, 0, stream>>>(accums, outf);
}

// Round 7
// 341.860 us; speedup vs baseline: 2.7163x; 1.2609x over previous
//
#include <hip/hip_runtime.h>
#include <math.h>

#define NU 100000
#define NI 50000
#define NN 150000
#define D 128
#define NE 1000000
#define CD 768
#define BATCH 4096

typedef short bf16x8 __attribute__((ext_vector_type(8)));
typedef float f32x4 __attribute__((ext_vector_type(4)));

static inline size_t alignup(size_t x, size_t a) { return (x + a - 1) / a * a; }

__device__ inline unsigned short f2bf(float f) {
  unsigned int u = __builtin_bit_cast(unsigned int, f);
  unsigned int r = (u + 0x7fffu + ((u >> 16) & 1u)) >> 16;
  return (unsigned short)r;
}
__device__ inline unsigned int pack2bf(float lo, float hi) {
  return (unsigned int)f2bf(lo) | ((unsigned int)f2bf(hi) << 16);
}
__device__ inline float bflo(unsigned int p) {
  return __builtin_bit_cast(float, p << 16);
}
__device__ inline float bfhi(unsigned int p) {
  return __builtin_bit_cast(float, p & 0xffff0000u);
}

// ---------------- fused prep: count+pos (even blocks) | xconv+wconv (odd blocks) ----------------
__global__ __launch_bounds__(256) void prep_kernel(
    const int* __restrict__ dst, int* __restrict__ cnt, int* __restrict__ cpos,
    const float* __restrict__ uemb, const float* __restrict__ iemb,
    unsigned int* __restrict__ x0b,
    const float* __restrict__ W, unsigned short* __restrict__ Wb) {
  int half = blockIdx.x >> 1;
  if ((blockIdx.x & 1) == 0) {
    int i = half * 256 + threadIdx.x;
    for (; i < NE; i += 2048 * 256)
      cpos[i] = atomicAdd(&cnt[dst[i]], 1);
  } else {
    const size_t XT = (size_t)NN * D / 8;
    const size_t WT = (size_t)D * CD / 8;
    size_t t = (size_t)half * 256 + threadIdx.x;
    for (; t < XT + WT; t += (size_t)2048 * 256) {
      if (t < XT) {
        size_t f = t * 8;
        const float* p = (f < (size_t)NU * D) ? (uemb + f) : (iemb + (f - (size_t)NU * D));
        float4 a = *(const float4*)p;
        float4 b = *(const float4*)(p + 4);
        uint4 o;
        o.x = pack2bf(a.x, a.y); o.y = pack2bf(a.z, a.w);
        o.z = pack2bf(b.x, b.y); o.w = pack2bf(b.z, b.w);
        *(uint4*)(x0b + t * 4) = o;
      } else {
        size_t f = (t - XT) * 8;
        float4 a = *(const float4*)(W + f);
        float4 b = *(const float4*)(W + f + 4);
        uint4 o;
        o.x = (unsigned int)f2bf(a.x) | ((unsigned int)f2bf(a.y) << 16);
        o.y = (unsigned int)f2bf(a.z) | ((unsigned int)f2bf(a.w) << 16);
        o.z = (unsigned int)f2bf(b.x) | ((unsigned int)f2bf(b.y) << 16);
        o.w = (unsigned int)f2bf(b.z) | ((unsigned int)f2bf(b.w) << 16);
        *(uint4*)(Wb + f) = o;
      }
    }
  }
}

// ---------------- prefix scan for CSR row_ptr ----------------

__global__ void scan_p1(const int* __restrict__ cnt, int* __restrict__ bsum) {
  __shared__ int s[256];
  int b = blockIdx.x;
  int i = b * 256 + threadIdx.x;
  s[threadIdx.x] = (i < NN) ? cnt[i] : 0;
  __syncthreads();
  for (int off = 128; off; off >>= 1) {
    if (threadIdx.x < off) s[threadIdx.x] += s[threadIdx.x + off];
    __syncthreads();
  }
  if (threadIdx.x == 0) bsum[b] = s[0];
}

__global__ __launch_bounds__(1024) void scan_p2(int* __restrict__ bsum, int nb) {
  __shared__ int s[1024];
  int t = threadIdx.x;
  int v = (t < nb) ? bsum[t] : 0;
  s[t] = v;
  __syncthreads();
  for (int off = 1; off < 1024; off <<= 1) {
    int u = (t >= off) ? s[t - off] : 0;
    __syncthreads();
    s[t] += u;
    __syncthreads();
  }
  if (t < nb) bsum[t] = s[t] - v;
}

__global__ void scan_p3(const int* __restrict__ cnt, const int* __restrict__ bsum,
                        int* __restrict__ row_ptr) {
  __shared__ int s[256];
  int b = blockIdx.x;
  int i = b * 256 + threadIdx.x;
  s[threadIdx.x] = (i < NN) ? cnt[i] : 0;
  __syncthreads();
  for (int off = 1; off < 256; off <<= 1) {
    int t = (threadIdx.x >= off) ? s[threadIdx.x - off] : 0;
    __syncthreads();
    s[threadIdx.x] += t;
    __syncthreads();
  }
  if (i < NN) row_ptr[i + 1] = bsum[b] + s[threadIdx.x];
  if (i == 0) row_ptr[0] = 0;
}

// ---------------- CSR fill (no atomics) ----------------
__global__ void fill_kernel(const int* __restrict__ src, const int* __restrict__ dst,
                            const float* __restrict__ ew, const int* __restrict__ row_ptr,
                            const int* __restrict__ cpos, int* __restrict__ csrc,
                            float* __restrict__ cew) {
  int i = blockIdx.x * blockDim.x + threadIdx.x;
  int stride = gridDim.x * blockDim.x;
  for (; i < NE; i += stride) {
    int p = row_ptr[dst[i]] + cpos[i];
    csrc[p] = src[i];
    cew[p] = ew[i];
  }
}

// ---------------- degree from CSR row sums + rsqrt ----------------
__global__ void degrow_kernel(const int* __restrict__ row_ptr, const float* __restrict__ cew,
                              float* __restrict__ dinv) {
  int n = blockIdx.x * blockDim.x + threadIdx.x;
  if (n >= NN) return;
  int beg = row_ptr[n], end = row_ptr[n + 1];
  float s = 0.f;
  for (int p = beg; p < end; ++p) s += cew[p];
  dinv[n] = (s > 0.f) ? rsqrtf(s) : 0.f;
}

// ---------------- per-slot partial norm: cnorm = dinv[src] * ew ----------------
__global__ void norm_kernel(const int* __restrict__ csrc, const float* __restrict__ cew,
                            const float* __restrict__ dinv, float* __restrict__ cnorm) {
  int i = blockIdx.x * blockDim.x + threadIdx.x;
  int stride = gridDim.x * blockDim.x;
  for (; i < NE; i += stride) cnorm[i] = dinv[csrc[i]] * cew[i];
}

// ---------------- propagation layers: 4 nodes/wave, 16 lanes/node, uint4 loads ----------------
#define GATHER_BODY(SRCBUF)                                                          \
  int tid = threadIdx.x;                                                             \
  int wv = tid >> 6, lane = tid & 63;                                                \
  int g = lane >> 4, sub = lane & 15;                                                \
  int n = blockIdx.x * 16 + wv * 4 + g;                                              \
  if (n >= NN) return;                                                               \
  int beg = row_ptr[n], end = row_ptr[n + 1];                                        \
  float a0 = 0.f, a1 = 0.f, a2 = 0.f, a3 = 0.f, a4 = 0.f, a5 = 0.f, a6 = 0.f, a7 = 0.f; \
  int j = beg;                                                                       \
  for (; j + 2 <= end; j += 2) {                                                     \
    int s0 = csrc[j], s1 = csrc[j + 1];                                              \
    float w0 = cnorm[j], w1 = cnorm[j + 1];                                          \
    uint4 p0 = SRCBUF[(size_t)s0 * 16 + sub];                                        \
    uint4 p1 = SRCBUF[(size_t)s1 * 16 + sub];                                        \
    a0 = fmaf(w0, bflo(p0.x), a0); a1 = fmaf(w0, bfhi(p0.x), a1);                    \
    a2 = fmaf(w0, bflo(p0.y), a2); a3 = fmaf(w0, bfhi(p0.y), a3);                    \
    a4 = fmaf(w0, bflo(p0.z), a4); a5 = fmaf(w0, bfhi(p0.z), a5);                    \
    a6 = fmaf(w0, bflo(p0.w), a6); a7 = fmaf(w0, bfhi(p0.w), a7);                    \
    a0 = fmaf(w1, bflo(p1.x), a0); a1 = fmaf(w1, bfhi(p1.x), a1);                    \
    a2 = fmaf(w1, bflo(p1.y), a2); a3 = fmaf(w1, bfhi(p1.y), a3);                    \
    a4 = fmaf(w1, bflo(p1.z), a4); a5 = fmaf(w1, bfhi(p1.z), a5);                    \
    a6 = fmaf(w1, bflo(p1.w), a6); a7 = fmaf(w1, bfhi(p1.w), a7);                    \
  }                                                                                  \
  if (j < end) {                                                                     \
    int s0 = csrc[j];                                                                \
    float w0 = cnorm[j];                                                             \
    uint4 p0 = SRCBUF[(size_t)s0 * 16 + sub];                                        \
    a0 = fmaf(w0, bflo(p0.x), a0); a1 = fmaf(w0, bfhi(p0.x), a1);                    \
    a2 = fmaf(w0, bflo(p0.y), a2); a3 = fmaf(w0, bfhi(p0.y), a3);                    \
    a4 = fmaf(w0, bflo(p0.z), a4); a5 = fmaf(w0, bfhi(p0.z), a5);                    \
    a6 = fmaf(w0, bflo(p0.w), a6); a7 = fmaf(w0, bfhi(p0.w), a7);                    \
  }

__global__ __launch_bounds__(256) void gather_kernel(
    const int* __restrict__ row_ptr, const int* __restrict__ csrc,
    const float* __restrict__ cnorm, const float* __restrict__ dinv,
    const uint4* __restrict__ xin, uint4* __restrict__ yout) {
  GATHER_BODY(xin)
  float sc = dinv[n];
  uint4 o;
  o.x = pack2bf(a0 * sc, a1 * sc);
  o.y = pack2bf(a2 * sc, a3 * sc);
  o.z = pack2bf(a4 * sc, a5 * sc);
  o.w = pack2bf(a6 * sc, a7 * sc);
  yout[(size_t)n * 16 + sub] = o;
}

// final layer: gather y3 from y2b, then OUT = 0.25*(x0+y1+y2+y3) in fp32
__global__ __launch_bounds__(256) void final_kernel(
    const int* __restrict__ row_ptr, const int* __restrict__ csrc,
    const float* __restrict__ cnorm, const float* __restrict__ dinv,
    const uint4* __restrict__ x0b, const uint4* __restrict__ y1b,
    const uint4* __restrict__ y2b, float* __restrict__ OUT) {
  GATHER_BODY(y2b)
  float sc = dinv[n];
  size_t r = (size_t)n * 16 + sub;
  uint4 q0 = x0b[r], q1 = y1b[r], q2 = y2b[r];
  float* op = OUT + (size_t)n * D + sub * 8;
  op[0] = (bflo(q0.x) + bflo(q1.x) + bflo(q2.x) + a0 * sc) * 0.25f;
  op[1] = (bfhi(q0.x) + bfhi(q1.x) + bfhi(q2.x) + a1 * sc) * 0.25f;
  op[2] = (bflo(q0.y) + bflo(q1.y) + bflo(q2.y) + a2 * sc) * 0.25f;
  op[3] = (bfhi(q0.y) + bfhi(q1.y) + bfhi(q2.y) + a3 * sc) * 0.25f;
  op[4] = (bflo(q0.z) + bflo(q1.z) + bflo(q2.z) + a4 * sc) * 0.25f;
  op[5] = (bfhi(q0.z) + bfhi(q1.z) + bfhi(q2.z) + a5 * sc) * 0.25f;
  op[6] = (bflo(q0.w) + bflo(q1.w) + bflo(q2.w) + a6 * sc) * 0.25f;
  op[7] = (bfhi(q0.w) + bfhi(q1.w) + bfhi(q2.w) + a7 * sc) * 0.25f;
}

// ---------------- content projection + align MSE (bf16 MFMA, double-buffered, 8 waves) ---------
__global__ __launch_bounds__(512) void align_mfma_kernel(
    const float* __restrict__ content, const unsigned short* __restrict__ Wb,
    const float* __restrict__ ifinal, float* __restrict__ accums) {
  __shared__ unsigned short Asm[2][64 * 64];
  __shared__ unsigned short Bsm[2][128 * 64];
  __shared__ float wred[8];

  int tid = threadIdx.x;
  int w = tid >> 6, lane = tid & 63;
  int i0 = blockIdx.x * 64;
  int lrow = lane & 15, kq = lane >> 4;

  f32x4 acc[4];
#pragma unroll
  for (int rt = 0; rt < 4; ++rt) acc[rt] = (f32x4){0.f, 0.f, 0.f, 0.f};

  int sr = tid >> 3, c8 = tid & 7;
  int arow_g = (i0 + sr < NI) ? (i0 + sr) : (NI - 1);
  const float* aG = content + (size_t)arow_g * CD + c8 * 8;
  const unsigned short* bG0 = Wb + (size_t)sr * CD + c8 * 8;
  const unsigned short* bG1 = Wb + (size_t)(sr + 64) * CD + c8 * 8;
  int aoff = (c8 * 16) ^ ((sr & 7) << 4);
  int boff0 = aoff;
  int boff1 = (c8 * 16) ^ (((sr + 64) & 7) << 4);

  {
    float4 a = *(const float4*)(aG);
    float4 b = *(const float4*)(aG + 4);
    uint4 o;
    o.x = pack2bf(a.x, a.y); o.y = pack2bf(a.z, a.w);
    o.z = pack2bf(b.x, b.y); o.w = pack2bf(b.z, b.w);
    *(uint4*)((char*)Asm[0] + sr * 128 + aoff) = o;
    *(uint4*)((char*)Bsm[0] + sr * 128 + boff0) = *(const uint4*)(bG0);
    *(uint4*)((char*)Bsm[0] + (sr + 64) * 128 + boff1) = *(const uint4*)(bG1);
  }

  for (int kk = 0; kk < 6; ++kk) {
    __syncthreads();
    int cur = kk & 1, nxt = cur ^ 1;
    bool more = kk < 5;
    float4 na, nb;
    uint4 nb0, nb1;
    if (more) {
      int k0 = (kk + 1) * 64;
      na = *(const float4*)(aG + k0);
      nb = *(const float4*)(aG + k0 + 4);
      nb0 = *(const uint4*)(bG0 + k0);
      nb1 = *(const uint4*)(bG1 + k0);
    }
#pragma unroll
    for (int ks = 0; ks < 2; ++ks) {
      int kbyte = ks * 64 + kq * 16;
      bf16x8 af[4], bfr;
#pragma unroll
      for (int rt = 0; rt < 4; ++rt) {
        int row = rt * 16 + lrow;
        af[rt] = *(const bf16x8*)((char*)Asm[cur] + row * 128 + (kbyte ^ ((row & 7) << 4)));
      }
      {
        int row = w * 16 + lrow;
        bfr = *(const bf16x8*)((char*)Bsm[cur] + row * 128 + (kbyte ^ ((row & 7) << 4)));
      }
#pragma unroll
      for (int rt = 0; rt < 4; ++rt)
        acc[rt] = __builtin_amdgcn_mfma_f32_16x16x32_bf16(af[rt], bfr, acc[rt], 0, 0, 0);
    }
    if (more) {
      uint4 o;
      o.x = pack2bf(na.x, na.y); o.y = pack2bf(na.z, na.w);
      o.z = pack2bf(nb.x, nb.y); o.w = pack2bf(nb.z, nb.w);
      *(uint4*)((char*)Asm[nxt] + sr * 128 + aoff) = o;
      *(uint4*)((char*)Bsm[nxt] + sr * 128 + boff0) = nb0;
      *(uint4*)((char*)Bsm[nxt] + (sr + 64) * 128 + boff1) = nb1;
    }
  }

  float s = 0.f;
  int dcol = w * 16 + lrow;
#pragma unroll
  for (int rt = 0; rt < 4; ++rt) {
#pragma unroll
    for (int j = 0; j < 4; ++j) {
      int it = i0 + rt * 16 + kq * 4 + j;
      if (it < NI) {
        float r0 = ifinal[(size_t)it * D + dcol];
        float d0 = r0 - acc[rt][j];
        s = fmaf(d0, d0, s);
      }
    }
  }
  for (int off = 32; off; off >>= 1) s += __shfl_down(s, off);
  if (lane == 0) wred[w] = s;
  __syncthreads();
  if (tid == 0) {
    float t = 0.f;
#pragma unroll
    for (int q = 0; q < 8; ++q) t += wred[q];
    atomicAdd(&accums[2], t);
  }
}

// ---------------- BPR + reg loss over batch (block-reduced atomics) ----------------
__global__ __launch_bounds__(256) void loss_batch(
    const int* __restrict__ bu, const int* __restrict__ bp, const int* __restrict__ bn,
    const float* __restrict__ OUT, float* __restrict__ accums) {
  __shared__ float wsp[4], wrg[4];
  int wv = threadIdx.x >> 6, lane = threadIdx.x & 63;
  int gw = blockIdx.x * 4 + wv;
  int nw = gridDim.x * 4;
  float lsp = 0.f, lrg = 0.f;
  for (int b = gw; b < BATCH; b += nw) {
    const float* u = OUT + (size_t)bu[b] * D;
    const float* ip = OUT + ((size_t)NU + bp[b]) * D;
    const float* in_ = OUT + ((size_t)NU + bn[b]) * D;
    float u0 = u[lane], u1 = u[lane + 64];
    float p0 = ip[lane], p1 = ip[lane + 64];
    float n0 = in_[lane], n1 = in_[lane + 64];
    float ps = u0 * p0 + u1 * p1;
    float ns = u0 * n0 + u1 * n1;
    float rg = u0 * u0 + u1 * u1 + p0 * p0 + p1 * p1 + n0 * n0 + n1 * n1;
    for (int off = 32; off; off >>= 1) {
      ps += __shfl_down(ps, off);
      ns += __shfl_down(ns, off);
      rg += __shfl_down(rg, off);
    }
    if (lane == 0) {
      float x = ns - ps;
      lsp += fmaxf(x, 0.f) + log1pf(expf(-fabsf(x)));
      lrg += rg;
    }
  }
  if (lane == 0) { wsp[wv] = lsp; wrg[wv] = lrg; }
  __syncthreads();
  if (threadIdx.x == 0) {
    atomicAdd(&accums[0], wsp[0] + wsp[1] + wsp[2] + wsp[3]);
    atomicAdd(&accums[1], wrg[0] + wrg[1] + wrg[2] + wrg[3]);
  }
}

__global__ void finalize_kernel(const float* __restrict__ accums, float* __restrict__ out0) {
  if (threadIdx.x == 0 && blockIdx.x == 0) {
    float bpr = accums[0] / (float)BATCH;
    float reg = (accums[1] / (float)BATCH) * 1e-4f;
    float align = accums[2] / (float)((size_t)NI * D);
    out0[0] = bpr + reg + 0.1f * align;
  }
}

// ---------------- launch ----------------
extern "C" void kernel_launch(void* const* d_in, const int* in_sizes, int n_in,
                              void* d_out, int out_size, void* d_ws, size_t ws_size,
                              hipStream_t stream) {
  const int* edge_index = (const int*)d_in[0];
  const float* ew = (const float*)d_in[1];
  const int* bu = (const int*)d_in[2];
  const int* bp = (const int*)d_in[3];
  const int* bn = (const int*)d_in[4];
  const float* content = (const float*)d_in[5];
  const float* uemb = (const float*)d_in[6];
  const float* iemb = (const float*)d_in[7];
  const float* W = (const float*)d_in[8];
  const int* src = edge_index;
  const int* dst = edge_index + NE;
  float* outf = (float*)d_out;
  float* OUT = outf + 1;  // [NN][D] fp32 (4B-aligned only!)

  char* ws = (char*)d_ws;
  size_t off = 0;
  auto alloc = [&](size_t bytes) {
    void* p = ws + off;
    off = alignup(off + bytes, 256);
    return p;
  };
  unsigned int* x0b = (unsigned int*)alloc((size_t)NN * 64 * 4);
  unsigned int* y1b = (unsigned int*)alloc((size_t)NN * 64 * 4);
  unsigned int* y2b = (unsigned int*)alloc((size_t)NN * 64 * 4);
  float* dinv = (float*)alloc((size_t)NN * 4);
  int* cnt = (int*)alloc((size_t)NN * 4);
  int* row_ptr = (int*)alloc((size_t)(NN + 1) * 4);
  int NB = (NN + 255) / 256;
  int* bsum = (int*)alloc((size_t)NB * 4);
  int* cpos = (int*)alloc((size_t)NE * 4);
  int* csrc = (int*)alloc((size_t)NE * 4);
  float* cew = (float*)alloc((size_t)NE * 4);
  float* cnorm = (float*)alloc((size_t)NE * 4);
  unsigned short* Wb = (unsigned short*)alloc((size_t)D * CD * 2);
  float* accums = (float*)alloc(16);

  hipMemsetAsync(cnt, 0, (size_t)NN * 4, stream);
  hipMemsetAsync(accums, 0, 16, stream);

  prep_kernel<<<4096, 256, 0, stream>>>(dst, cnt, cpos, uemb, iemb, x0b, W, Wb);
  scan_p1<<<NB, 256, 0, stream>>>(cnt, bsum);
  scan_p2<<<1, 1024, 0, stream>>>(bsum, NB);
  scan_p3<<<NB, 256, 0, stream>>>(cnt, bsum, row_ptr);
  fill_kernel<<<2048, 256, 0, stream>>>(src, dst, ew, row_ptr, cpos, csrc, cew);
  degrow_kernel<<<NB, 256, 0, stream>>>(row_ptr, cew, dinv);
  norm_kernel<<<2048, 256, 0, stream>>>(csrc, cew, dinv, cnorm);

  int LB = (NN + 15) / 16;
  gather_kernel<<<LB, 256, 0, stream>>>(row_ptr, csrc, cnorm, dinv, (const uint4*)x0b, (uint4*)y1b);
  gather_kernel<<<LB, 256, 0, stream>>>(row_ptr, csrc, cnorm, dinv, (const uint4*)y1b, (uint4*)y2b);
  final_kernel<<<LB, 256, 0, stream>>>(row_ptr, csrc, cnorm, dinv,
                                       (const uint4*)x0b, (const uint4*)y1b, (const uint4*)y2b, OUT);

  align_mfma_kernel<<<(NI + 63) / 64, 512, 0, stream>>>(content, Wb, OUT + (size_t)NU * D, accums);
  loss_batch<<<64, 256, 0, stream>>>(bu, bp, bn, OUT, accums);
  finalize_kernel<<<1, 64, 0, stream>>>(accums, outf);
}

// Round 8
// 324.808 us; speedup vs baseline: 2.8589x; 1.0525x over previous
//
#include <hip/hip_runtime.h>
#include <math.h>

#define NU 100000
#define NI 50000
#define NN 150000
#define D 128
#define NE 1000000
#define CD 768
#define BATCH 4096
#define NGEMM 782  // ceil(NI/64)

typedef short bf16x8 __attribute__((ext_vector_type(8)));
typedef float f32x4 __attribute__((ext_vector_type(4)));

static inline size_t alignup(size_t x, size_t a) { return (x + a - 1) / a * a; }

__device__ inline unsigned short f2bf(float f) {
  unsigned int u = __builtin_bit_cast(unsigned int, f);
  unsigned int r = (u + 0x7fffu + ((u >> 16) & 1u)) >> 16;
  return (unsigned short)r;
}
__device__ inline unsigned int pack2bf(float lo, float hi) {
  return (unsigned int)f2bf(lo) | ((unsigned int)f2bf(hi) << 16);
}
__device__ inline float bflo(unsigned int p) {
  return __builtin_bit_cast(float, p << 16);
}
__device__ inline float bfhi(unsigned int p) {
  return __builtin_bit_cast(float, p & 0xffff0000u);
}

// ---------------- 3-arm prep ----------------
// blocks [0,NGEMM): content@W.T GEMM -> proj (bf16)
// blocks >= NGEMM, even: edge count + position capture (atomics)
// blocks >= NGEMM, odd:  x0 bf16 conversion (streaming)
__global__ __launch_bounds__(512) void prep_kernel(
    const int* __restrict__ dst, int* __restrict__ cnt, int* __restrict__ cpos,
    const float* __restrict__ uemb, const float* __restrict__ iemb,
    unsigned int* __restrict__ x0b,
    const float* __restrict__ W, const float* __restrict__ content,
    uint4* __restrict__ proj) {
  __shared__ unsigned short Asm[2][64 * 64];   // also reused as 64x128 transpose buf
  __shared__ unsigned short Bsm[2][128 * 64];

  int bid = blockIdx.x;
  int tid = threadIdx.x;

  if (bid >= NGEMM) {
    int sub = bid - NGEMM;
    int half = sub >> 1;
    if ((sub & 1) == 0) {
      // ---- atomic arm: the only atomics in the CSR build
      int i = half * 512 + tid;
      for (; i < NE; i += 1024 * 512)
        cpos[i] = atomicAdd(&cnt[dst[i]], 1);
    } else {
      // ---- x0 conversion arm
      const size_t XT = (size_t)NN * D / 8;
      size_t t = (size_t)half * 512 + tid;
      for (; t < XT; t += (size_t)1024 * 512) {
        size_t f = t * 8;
        const float* p = (f < (size_t)NU * D) ? (uemb + f) : (iemb + (f - (size_t)NU * D));
        float4 a = *(const float4*)p;
        float4 b = *(const float4*)(p + 4);
        uint4 o;
        o.x = pack2bf(a.x, a.y); o.y = pack2bf(a.z, a.w);
        o.z = pack2bf(b.x, b.y); o.w = pack2bf(b.z, b.w);
        *(uint4*)(x0b + t * 4) = o;
      }
    }
    return;
  }

  // ---- GEMM arm: 64 items x 128 D, BK=64, double-buffered, 8 waves ----
  int w = tid >> 6, lane = tid & 63;
  int i0 = bid * 64;
  int lrow = lane & 15, kq = lane >> 4;

  f32x4 acc[4];
#pragma unroll
  for (int rt = 0; rt < 4; ++rt) acc[rt] = (f32x4){0.f, 0.f, 0.f, 0.f};

  int sr = tid >> 3, c8 = tid & 7;
  int arow_g = (i0 + sr < NI) ? (i0 + sr) : (NI - 1);
  const float* aG = content + (size_t)arow_g * CD + c8 * 8;
  const float* bG0 = W + (size_t)sr * CD + c8 * 8;
  const float* bG1 = W + (size_t)(sr + 64) * CD + c8 * 8;
  int aoff = (c8 * 16) ^ ((sr & 7) << 4);
  int boff0 = aoff;
  int boff1 = (c8 * 16) ^ (((sr + 64) & 7) << 4);

  // prologue: stage k0=0 into buffer 0 (fp32 -> bf16 for A and both B rows)
  {
    float4 a0 = *(const float4*)(aG);
    float4 a1 = *(const float4*)(aG + 4);
    float4 p0 = *(const float4*)(bG0);
    float4 p1 = *(const float4*)(bG0 + 4);
    float4 q0 = *(const float4*)(bG1);
    float4 q1 = *(const float4*)(bG1 + 4);
    uint4 oa, ob, oc;
    oa.x = pack2bf(a0.x, a0.y); oa.y = pack2bf(a0.z, a0.w);
    oa.z = pack2bf(a1.x, a1.y); oa.w = pack2bf(a1.z, a1.w);
    ob.x = pack2bf(p0.x, p0.y); ob.y = pack2bf(p0.z, p0.w);
    ob.z = pack2bf(p1.x, p1.y); ob.w = pack2bf(p1.z, p1.w);
    oc.x = pack2bf(q0.x, q0.y); oc.y = pack2bf(q0.z, q0.w);
    oc.z = pack2bf(q1.x, q1.y); oc.w = pack2bf(q1.z, q1.w);
    *(uint4*)((char*)Asm[0] + sr * 128 + aoff) = oa;
    *(uint4*)((char*)Bsm[0] + sr * 128 + boff0) = ob;
    *(uint4*)((char*)Bsm[0] + (sr + 64) * 128 + boff1) = oc;
  }

  for (int kk = 0; kk < 6; ++kk) {
    __syncthreads();
    int cur = kk & 1, nxt = cur ^ 1;
    bool more = kk < 5;
    float4 a0, a1, p0, p1, q0, q1;
    if (more) {
      int k0 = (kk + 1) * 64;
      a0 = *(const float4*)(aG + k0);
      a1 = *(const float4*)(aG + k0 + 4);
      p0 = *(const float4*)(bG0 + k0);
      p1 = *(const float4*)(bG0 + k0 + 4);
      q0 = *(const float4*)(bG1 + k0);
      q1 = *(const float4*)(bG1 + k0 + 4);
    }
#pragma unroll
    for (int ks = 0; ks < 2; ++ks) {
      int kbyte = ks * 64 + kq * 16;
      bf16x8 af[4], bfr;
#pragma unroll
      for (int rt = 0; rt < 4; ++rt) {
        int row = rt * 16 + lrow;
        af[rt] = *(const bf16x8*)((char*)Asm[cur] + row * 128 + (kbyte ^ ((row & 7) << 4)));
      }
      {
        int row = w * 16 + lrow;
        bfr = *(const bf16x8*)((char*)Bsm[cur] + row * 128 + (kbyte ^ ((row & 7) << 4)));
      }
#pragma unroll
      for (int rt = 0; rt < 4; ++rt)
        acc[rt] = __builtin_amdgcn_mfma_f32_16x16x32_bf16(af[rt], bfr, acc[rt], 0, 0, 0);
    }
    if (more) {
      uint4 oa, ob, oc;
      oa.x = pack2bf(a0.x, a0.y); oa.y = pack2bf(a0.z, a0.w);
      oa.z = pack2bf(a1.x, a1.y); oa.w = pack2bf(a1.z, a1.w);
      ob.x = pack2bf(p0.x, p0.y); ob.y = pack2bf(p0.z, p0.w);
      ob.z = pack2bf(p1.x, p1.y); ob.w = pack2bf(p1.z, p1.w);
      oc.x = pack2bf(q0.x, q0.y); oc.y = pack2bf(q0.z, q0.w);
      oc.z = pack2bf(q1.x, q1.y); oc.w = pack2bf(q1.z, q1.w);
      *(uint4*)((char*)Asm[nxt] + sr * 128 + aoff) = oa;
      *(uint4*)((char*)Bsm[nxt] + sr * 128 + boff0) = ob;
      *(uint4*)((char*)Bsm[nxt] + (sr + 64) * 128 + boff1) = oc;
    }
  }

  // ---- epilogue: transpose acc through LDS, store proj rows as bf16 uint4 ----
  // C/D layout: D-col = w*16 + lrow, item-row = rt*16 + kq*4 + j
  __syncthreads();
  unsigned short* T = (unsigned short*)Asm;  // [64][128] = 16 KB
  int dcol = w * 16 + lrow;
#pragma unroll
  for (int rt = 0; rt < 4; ++rt)
#pragma unroll
    for (int j = 0; j < 4; ++j)
      T[(rt * 16 + kq * 4 + j) * 128 + dcol] = f2bf(acc[rt][j]);
  __syncthreads();
#pragma unroll
  for (int u0 = 0; u0 < 2; ++u0) {
    int u = u0 * 512 + tid;
    int r = u >> 4, s = u & 15;
    int it = i0 + r;
    if (it < NI) proj[(size_t)it * 16 + s] = ((const uint4*)T)[u];
  }
}

// ---------------- prefix scan for CSR row_ptr ----------------

__global__ void scan_p1(const int* __restrict__ cnt, int* __restrict__ bsum) {
  __shared__ int s[256];
  int b = blockIdx.x;
  int i = b * 256 + threadIdx.x;
  s[threadIdx.x] = (i < NN) ? cnt[i] : 0;
  __syncthreads();
  for (int off = 128; off; off >>= 1) {
    if (threadIdx.x < off) s[threadIdx.x] += s[threadIdx.x + off];
    __syncthreads();
  }
  if (threadIdx.x == 0) bsum[b] = s[0];
}

__global__ __launch_bounds__(1024) void scan_p2(int* __restrict__ bsum, int nb) {
  __shared__ int s[1024];
  int t = threadIdx.x;
  int v = (t < nb) ? bsum[t] : 0;
  s[t] = v;
  __syncthreads();
  for (int off = 1; off < 1024; off <<= 1) {
    int u = (t >= off) ? s[t - off] : 0;
    __syncthreads();
    s[t] += u;
    __syncthreads();
  }
  if (t < nb) bsum[t] = s[t] - v;
}

__global__ void scan_p3(const int* __restrict__ cnt, const int* __restrict__ bsum,
                        int* __restrict__ row_ptr) {
  __shared__ int s[256];
  int b = blockIdx.x;
  int i = b * 256 + threadIdx.x;
  s[threadIdx.x] = (i < NN) ? cnt[i] : 0;
  __syncthreads();
  for (int off = 1; off < 256; off <<= 1) {
    int t = (threadIdx.x >= off) ? s[threadIdx.x - off] : 0;
    __syncthreads();
    s[threadIdx.x] += t;
    __syncthreads();
  }
  if (i < NN) row_ptr[i + 1] = bsum[b] + s[threadIdx.x];
  if (i == 0) row_ptr[0] = 0;
}

// ---------------- CSR fill (no atomics) ----------------
__global__ void fill_kernel(const int* __restrict__ src, const int* __restrict__ dst,
                            const float* __restrict__ ew, const int* __restrict__ row_ptr,
                            const int* __restrict__ cpos, int* __restrict__ csrc,
                            float* __restrict__ cew) {
  int i = blockIdx.x * blockDim.x + threadIdx.x;
  int stride = gridDim.x * blockDim.x;
  for (; i < NE; i += stride) {
    int p = row_ptr[dst[i]] + cpos[i];
    csrc[p] = src[i];
    cew[p] = ew[i];
  }
}

// ---------------- degree from CSR row sums + rsqrt ----------------
__global__ void degrow_kernel(const int* __restrict__ row_ptr, const float* __restrict__ cew,
                              float* __restrict__ dinv) {
  int n = blockIdx.x * blockDim.x + threadIdx.x;
  if (n >= NN) return;
  int beg = row_ptr[n], end = row_ptr[n + 1];
  float s = 0.f;
  for (int p = beg; p < end; ++p) s += cew[p];
  dinv[n] = (s > 0.f) ? rsqrtf(s) : 0.f;
}

// ---------------- per-slot partial norm: cnorm = dinv[src] * ew ----------------
__global__ void norm_kernel(const int* __restrict__ csrc, const float* __restrict__ cew,
                            const float* __restrict__ dinv, float* __restrict__ cnorm) {
  int i = blockIdx.x * blockDim.x + threadIdx.x;
  int stride = gridDim.x * blockDim.x;
  for (; i < NE; i += stride) cnorm[i] = dinv[csrc[i]] * cew[i];
}

// ---------------- propagation layers: 4 nodes/wave, 16 lanes/node, uint4 loads ----------------
#define GATHER_BODY(SRCBUF)                                                          \
  int tid = threadIdx.x;                                                             \
  int wv = tid >> 6, lane = tid & 63;                                                \
  int g = lane >> 4, sub = lane & 15;                                                \
  int n = blockIdx.x * 16 + wv * 4 + g;                                              \
  if (n >= NN) return;                                                               \
  int beg = row_ptr[n], end = row_ptr[n + 1];                                        \
  float a0 = 0.f, a1 = 0.f, a2 = 0.f, a3 = 0.f, a4 = 0.f, a5 = 0.f, a6 = 0.f, a7 = 0.f; \
  int j = beg;                                                                       \
  for (; j + 2 <= end; j += 2) {                                                     \
    int s0 = csrc[j], s1 = csrc[j + 1];                                              \
    float w0 = cnorm[j], w1 = cnorm[j + 1];                                          \
    uint4 p0 = SRCBUF[(size_t)s0 * 16 + sub];                                        \
    uint4 p1 = SRCBUF[(size_t)s1 * 16 + sub];                                        \
    a0 = fmaf(w0, bflo(p0.x), a0); a1 = fmaf(w0, bfhi(p0.x), a1);                    \
    a2 = fmaf(w0, bflo(p0.y), a2); a3 = fmaf(w0, bfhi(p0.y), a3);                    \
    a4 = fmaf(w0, bflo(p0.z), a4); a5 = fmaf(w0, bfhi(p0.z), a5);                    \
    a6 = fmaf(w0, bflo(p0.w), a6); a7 = fmaf(w0, bfhi(p0.w), a7);                    \
    a0 = fmaf(w1, bflo(p1.x), a0); a1 = fmaf(w1, bfhi(p1.x), a1);                    \
    a2 = fmaf(w1, bflo(p1.y), a2); a3 = fmaf(w1, bfhi(p1.y), a3);                    \
    a4 = fmaf(w1, bflo(p1.z), a4); a5 = fmaf(w1, bfhi(p1.z), a5);                    \
    a6 = fmaf(w1, bflo(p1.w), a6); a7 = fmaf(w1, bfhi(p1.w), a7);                    \
  }                                                                                  \
  if (j < end) {                                                                     \
    int s0 = csrc[j];                                                                \
    float w0 = cnorm[j];                                                             \
    uint4 p0 = SRCBUF[(size_t)s0 * 16 + sub];                                        \
    a0 = fmaf(w0, bflo(p0.x), a0); a1 = fmaf(w0, bfhi(p0.x), a1);                    \
    a2 = fmaf(w0, bflo(p0.y), a2); a3 = fmaf(w0, bfhi(p0.y), a3);                    \
    a4 = fmaf(w0, bflo(p0.z), a4); a5 = fmaf(w0, bfhi(p0.z), a5);                    \
    a6 = fmaf(w0, bflo(p0.w), a6); a7 = fmaf(w0, bfhi(p0.w), a7);                    \
  }

__global__ __launch_bounds__(256) void gather_kernel(
    const int* __restrict__ row_ptr, const int* __restrict__ csrc,
    const float* __restrict__ cnorm, const float* __restrict__ dinv,
    const uint4* __restrict__ xin, uint4* __restrict__ yout) {
  GATHER_BODY(xin)
  float sc = dinv[n];
  uint4 o;
  o.x = pack2bf(a0 * sc, a1 * sc);
  o.y = pack2bf(a2 * sc, a3 * sc);
  o.z = pack2bf(a4 * sc, a5 * sc);
  o.w = pack2bf(a6 * sc, a7 * sc);
  yout[(size_t)n * 16 + sub] = o;
}

// final layer: gather y3, OUT = 0.25*(x0+y1+y2+y3), fused align-MSE for item rows
__global__ __launch_bounds__(256) void final_kernel(
    const int* __restrict__ row_ptr, const int* __restrict__ csrc,
    const float* __restrict__ cnorm, const float* __restrict__ dinv,
    const uint4* __restrict__ x0b, const uint4* __restrict__ y1b,
    const uint4* __restrict__ y2b, const uint4* __restrict__ proj,
    float* __restrict__ OUT, float* __restrict__ partials) {
  __shared__ float wred[4];
  GATHER_BODY(y2b)
  float sc = dinv[n];
  size_t r = (size_t)n * 16 + sub;
  uint4 q0 = x0b[r], q1 = y1b[r], q2 = y2b[r];
  float v[8];
  v[0] = (bflo(q0.x) + bflo(q1.x) + bflo(q2.x) + a0 * sc) * 0.25f;
  v[1] = (bfhi(q0.x) + bfhi(q1.x) + bfhi(q2.x) + a1 * sc) * 0.25f;
  v[2] = (bflo(q0.y) + bflo(q1.y) + bflo(q2.y) + a2 * sc) * 0.25f;
  v[3] = (bfhi(q0.y) + bfhi(q1.y) + bfhi(q2.y) + a3 * sc) * 0.25f;
  v[4] = (bflo(q0.z) + bflo(q1.z) + bflo(q2.z) + a4 * sc) * 0.25f;
  v[5] = (bfhi(q0.z) + bfhi(q1.z) + bfhi(q2.z) + a5 * sc) * 0.25f;
  v[6] = (bflo(q0.w) + bflo(q1.w) + bflo(q2.w) + a6 * sc) * 0.25f;
  v[7] = (bfhi(q0.w) + bfhi(q1.w) + bfhi(q2.w) + a7 * sc) * 0.25f;
  float* op = OUT + (size_t)n * D + sub * 8;
#pragma unroll
  for (int k = 0; k < 8; ++k) op[k] = v[k];

  // item blocks are exactly blockIdx.x >= NU/16 (NU divisible by 16)
  if (blockIdx.x >= (NU / 16)) {
    uint4 pj = proj[(size_t)(n - NU) * 16 + sub];
    float d0 = v[0] - bflo(pj.x), d1 = v[1] - bfhi(pj.x);
    float d2 = v[2] - bflo(pj.y), d3 = v[3] - bfhi(pj.y);
    float d4 = v[4] - bflo(pj.z), d5 = v[5] - bfhi(pj.z);
    float d6 = v[6] - bflo(pj.w), d7 = v[7] - bfhi(pj.w);
    float m = d0 * d0 + d1 * d1 + d2 * d2 + d3 * d3 + d4 * d4 + d5 * d5 + d6 * d6 + d7 * d7;
    for (int off = 32; off; off >>= 1) m += __shfl_down(m, off);
    if (lane == 0) wred[wv] = m;
    __syncthreads();
    if (tid == 0)
      atomicAdd(&partials[blockIdx.x & 255], wred[0] + wred[1] + wred[2] + wred[3]);
  }
}

// ---------------- BPR + reg loss over batch (block-reduced atomics) ----------------
__global__ __launch_bounds__(256) void loss_batch(
    const int* __restrict__ bu, const int* __restrict__ bp, const int* __restrict__ bn,
    const float* __restrict__ OUT, float* __restrict__ accums) {
  __shared__ float wsp[4], wrg[4];
  int wv = threadIdx.x >> 6, lane = threadIdx.x & 63;
  int gw = blockIdx.x * 4 + wv;
  int nw = gridDim.x * 4;
  float lsp = 0.f, lrg = 0.f;
  for (int b = gw; b < BATCH; b += nw) {
    const float* u = OUT + (size_t)bu[b] * D;
    const float* ip = OUT + ((size_t)NU + bp[b]) * D;
    const float* in_ = OUT + ((size_t)NU + bn[b]) * D;
    float u0 = u[lane], u1 = u[lane + 64];
    float p0 = ip[lane], p1 = ip[lane + 64];
    float n0 = in_[lane], n1 = in_[lane + 64];
    float ps = u0 * p0 + u1 * p1;
    float ns = u0 * n0 + u1 * n1;
    float rg = u0 * u0 + u1 * u1 + p0 * p0 + p1 * p1 + n0 * n0 + n1 * n1;
    for (int off = 32; off; off >>= 1) {
      ps += __shfl_down(ps, off);
      ns += __shfl_down(ns, off);
      rg += __shfl_down(rg, off);
    }
    if (lane == 0) {
      float x = ns - ps;
      lsp += fmaxf(x, 0.f) + log1pf(expf(-fabsf(x)));
      lrg += rg;
    }
  }
  if (lane == 0) { wsp[wv] = lsp; wrg[wv] = lrg; }
  __syncthreads();
  if (threadIdx.x == 0) {
    atomicAdd(&accums[0], wsp[0] + wsp[1] + wsp[2] + wsp[3]);
    atomicAdd(&accums[1], wrg[0] + wrg[1] + wrg[2] + wrg[3]);
  }
}

__global__ void finalize_kernel(const float* __restrict__ accums,
                                const float* __restrict__ partials,
                                float* __restrict__ out0) {
  __shared__ float sm[4];
  int tid = threadIdx.x;
  float v = partials[tid];
  for (int off = 32; off; off >>= 1) v += __shfl_down(v, off);
  if ((tid & 63) == 0) sm[tid >> 6] = v;
  __syncthreads();
  if (tid == 0) {
    float align_sum = sm[0] + sm[1] + sm[2] + sm[3];
    float bpr = accums[0] / (float)BATCH;
    float reg = (accums[1] / (float)BATCH) * 1e-4f;
    float align = align_sum / (float)((size_t)NI * D);
    out0[0] = bpr + reg + 0.1f * align;
  }
}

// ---------------- launch ----------------
extern "C" void kernel_launch(void* const* d_in, const int* in_sizes, int n_in,
                              void* d_out, int out_size, void* d_ws, size_t ws_size,
                              hipStream_t stream) {
  const int* edge_index = (const int*)d_in[0];
  const float* ew = (const float*)d_in[1];
  const int* bu = (const int*)d_in[2];
  const int* bp = (const int*)d_in[3];
  const int* bn = (const int*)d_in[4];
  const float* content = (const float*)d_in[5];
  const float* uemb = (const float*)d_in[6];
  const float* iemb = (const float*)d_in[7];
  const float* W = (const float*)d_in[8];
  const int* src = edge_index;
  const int* dst = edge_index + NE;
  float* outf = (float*)d_out;
  float* OUT = outf + 1;  // [NN][D] fp32 (4B-aligned only!)

  char* ws = (char*)d_ws;
  size_t off = 0;
  auto alloc = [&](size_t bytes) {
    void* p = ws + off;
    off = alignup(off + bytes, 256);
    return p;
  };
  unsigned int* x0b = (unsigned int*)alloc((size_t)NN * 64 * 4);
  unsigned int* y1b = (unsigned int*)alloc((size_t)NN * 64 * 4);
  unsigned int* y2b = (unsigned int*)alloc((size_t)NN * 64 * 4);
  uint4* proj = (uint4*)alloc((size_t)NI * 16 * 16);
  float* dinv = (float*)alloc((size_t)NN * 4);
  int* cnt = (int*)alloc((size_t)NN * 4);
  int* row_ptr = (int*)alloc((size_t)(NN + 1) * 4);
  int NB = (NN + 255) / 256;
  int* bsum = (int*)alloc((size_t)NB * 4);
  int* cpos = (int*)alloc((size_t)NE * 4);
  int* csrc = (int*)alloc((size_t)NE * 4);
  float* cew = (float*)alloc((size_t)NE * 4);
  float* cnorm = (float*)alloc((size_t)NE * 4);
  float* accums = (float*)alloc(16 + 256 * 4);  // [0..3] accums, [4..259] mse partials
  float* partials = accums + 4;

  hipMemsetAsync(cnt, 0, (size_t)NN * 4, stream);
  hipMemsetAsync(accums, 0, 16 + 256 * 4, stream);

  prep_kernel<<<NGEMM + 2048, 512, 0, stream>>>(dst, cnt, cpos, uemb, iemb, x0b, W, content, proj);
  scan_p1<<<NB, 256, 0, stream>>>(cnt, bsum);
  scan_p2<<<1, 1024, 0, stream>>>(bsum, NB);
  scan_p3<<<NB, 256, 0, stream>>>(cnt, bsum, row_ptr);
  fill_kernel<<<2048, 256, 0, stream>>>(src, dst, ew, row_ptr, cpos, csrc, cew);
  degrow_kernel<<<NB, 256, 0, stream>>>(row_ptr, cew, dinv);
  norm_kernel<<<2048, 256, 0, stream>>>(csrc, cew, dinv, cnorm);

  int LB = (NN + 15) / 16;
  gather_kernel<<<LB, 256, 0, stream>>>(row_ptr, csrc, cnorm, dinv, (const uint4*)x0b, (uint4*)y1b);
  gather_kernel<<<LB, 256, 0, stream>>>(row_ptr, csrc, cnorm, dinv, (const uint4*)y1b, (uint4*)y2b);
  final_kernel<<<LB, 256, 0, stream>>>(row_ptr, csrc, cnorm, dinv,
                                       (const uint4*)x0b, (const uint4*)y1b, (const uint4*)y2b,
                                       proj, OUT, partials);

  loss_batch<<<64, 256, 0, stream>>>(bu, bp, bn, OUT, accums);
  finalize_kernel<<<1, 256, 0, stream>>>(accums, partials, outf);
}